// Round 9
// baseline (225.019 us; speedup 1.0000x reference)
//
#include <hip/hip_runtime.h>
#include <hip/hip_bf16.h>
#include <cstdint>
#include <cstddef>

typedef short short8 __attribute__((ext_vector_type(8)));
typedef float floatx4 __attribute__((ext_vector_type(4)));
typedef float floatx16 __attribute__((ext_vector_type(16)));
typedef int intx4 __attribute__((ext_vector_type(4)));
typedef unsigned short u16;
typedef unsigned int u32;

__device__ __forceinline__ u16 f2bf(float f) {
    __hip_bfloat16 h = __float2bfloat16(f);
    return __builtin_bit_cast(u16, h);
}

__device__ __forceinline__ void gload_lds16(const void* g, void* l) {
    __builtin_amdgcn_global_load_lds(
        (const __attribute__((address_space(1))) void*)g,
        (__attribute__((address_space(3))) void*)l, 16, 0, 0);
}

// ---------------- fp32 -> bf16 elementwise ----------------
__global__ __launch_bounds__(256) void cvt_x(const float* __restrict__ in, u16* __restrict__ out, int n4) {
    int stride = gridDim.x * blockDim.x;
    for (int i = blockIdx.x * blockDim.x + threadIdx.x; i < n4; i += stride) {
        float4 v = ((const float4*)in)[i];
        ushort4 o;
        o.x = f2bf(v.x); o.y = f2bf(v.y); o.z = f2bf(v.z); o.w = f2bf(v.w);
        ((ushort4*)out)[i] = o;
    }
}

// ---------------- W[K][N] f32 -> Wt[N][K] bf16 ----------------
__global__ __launch_bounds__(256) void transpose_cvt(const float* __restrict__ W, u16* __restrict__ Wt,
                                                     int K, int N) {
    __shared__ float tile[32][33];
    int n0 = blockIdx.x * 32, k0 = blockIdx.y * 32;
    int tx = threadIdx.x & 31, ty = threadIdx.x >> 5;  // ty 0..7
    #pragma unroll
    for (int i = 0; i < 32; i += 8)
        tile[ty + i][tx] = W[(size_t)(k0 + ty + i) * N + n0 + tx];
    __syncthreads();
    #pragma unroll
    for (int i = 0; i < 32; i += 8)
        Wt[(size_t)(n0 + ty + i) * K + k0 + tx] = f2bf(tile[tx][ty + i]);
}

// ---------------- 256x256 8-phase bf16 GEMM: C = A[M][K] * Bt[N][K]^T ----------------
// BK=64, 512 threads = 8 waves (2M x 4N), wave tile 128x64, acc 8x4 floatx4.
// LDS = 2 dbufs x (A 256x64 + B 256x64) x 2B = 128 KB, chunk-XOR involution
// (position q = chunk c ^ ((c>>3)&7), row-group-local; 0-conflict measured r6-r8).
// Iteration = 2 K-tiles; 8 phases, each: {ds-read quadrant frags | stage 1 quarter-
// unit (2 gload_lds)} -> barrier -> 16 MFMA (setprio) -> barrier. vmcnt(4) only at
// phases 4/8 (2 units = 4 loads stay in flight across barriers; never drains).
// Staging units match read/death sets exactly:
//   A unit mh = rows [mh*64,+64) U [128+mh*64,+64)   (read only in phases with that mh)
//   B unit nh = rows [wcb*64+nh*32,+32) for wcb=0..3 (read only in phases with that nh)
// Slot schedule (iteration i; t1=2i+1, t2=2i+2, t3=2i+3 clamped):
//   s1:A(d1,mh1,t1) s2:B(d1,nh0,t1) s3:A(d0,mh0,t2) s4:B(d0,nh1,t2)
//   s5:A(d0,mh1,t2) s6:B(d0,nh0,t2) s7:A(d1,mh0,t3) s8:B(d1,nh1,t3)
// Every slot overwrites a unit whose last reader finished >=1 end-barrier earlier.
// MODE: 0 = f32 [M][N]; 4 = col<1024 -> per-head packed q [b][h][t][64],
//       1024<=col<1152 -> latent [M][128] appended after q; col>=1152 discarded.
template <int MODE>
__global__ __launch_bounds__(512, 2) void gemm8p(const u16* __restrict__ A, const u16* __restrict__ Bt,
                                                 void* __restrict__ C, int M, int N, int K, int nwgx) {
    __shared__ __align__(16) u16 lds[65536];  // 128 KB
    const int tid = threadIdx.x;
    const int lane = tid & 63, wid = tid >> 6;
    const int wr = wid >> 2, wc = wid & 3;
    const int l15 = lane & 15, hi = lane >> 4;

    // bijective XCD swizzle (nwg % 8 == 0)
    const int nwg = gridDim.x;
    const int qch = nwg >> 3;
    const int wg = (blockIdx.x & 7) * qch + (blockIdx.x >> 3);
    const int mx = wg % nwgx, nx = wg / nwgx;
    const int m0 = mx * 256, n0 = nx * 256;

    const u16* Ab = A + (size_t)m0 * K;
    const u16* Bb = Bt + (size_t)n0 * K;

    // ---- staging (source carries the involution; LDS dest is linear per load) ----
    auto SA = [&](int kt, int d, int mh) {  // A unit mh -> dbuf d
        u16* base = &lds[d * 32768];
        #pragma unroll
        for (int l = 0; l < 2; l++) {
            int p = l * 1024 + mh * 512 + tid;           // position chunk
            int c = p ^ ((p >> 3) & 7);                  // source chunk (involution)
            const u16* src = Ab + (size_t)(c >> 3) * K + (c & 7) * 8 + kt * 64;
            gload_lds16(src, base + (l * 1024 + mh * 512 + wid * 64) * 8);
        }
    };
    auto SB = [&](int kt, int d, int nh) {  // B unit nh -> dbuf d
        u16* base = &lds[d * 32768 + 16384];
        #pragma unroll
        for (int l = 0; l < 2; l++) {
            int wcb = l * 2 + (wid >> 2);                // wave-uniform
            int p = wcb * 512 + nh * 256 + (wid & 3) * 64 + lane;
            int c = p ^ ((p >> 3) & 7);
            const u16* src = Bb + (size_t)(c >> 3) * K + (c & 7) * 8 + kt * 64;
            gload_lds16(src, base + (wcb * 512 + nh * 256 + (wid & 3) * 64) * 8);
        }
    };

    // ---- fragment read offsets (q = c ^ (row&7), c = row*8 + ks*4 + hi) ----
    auto AOFF = [&](int d, int mt, int ks) {
        int row = wr * 128 + mt * 16 + l15;
        int q = (row * 8 + ks * 4 + hi) ^ (row & 7);
        return d * 32768 + q * 8;
    };
    auto BOFF = [&](int d, int nt, int ks) {
        int row = wc * 64 + nt * 16 + l15;
        int q = (row * 8 + ks * 4 + hi) ^ (row & 7);
        return d * 32768 + 16384 + q * 8;
    };

    short8 afr[4][2], bfr[2][2];
    floatx4 acc[8][4] = {};

    auto LOAD_A = [&](int d, int mh) {
        #pragma unroll
        for (int j = 0; j < 4; j++)
            #pragma unroll
            for (int ks = 0; ks < 2; ks++)
                afr[j][ks] = *(const short8*)&lds[AOFF(d, mh * 4 + j, ks)];
    };
    auto LOAD_B = [&](int d, int nh) {
        #pragma unroll
        for (int n = 0; n < 2; n++)
            #pragma unroll
            for (int ks = 0; ks < 2; ks++)
                bfr[n][ks] = *(const short8*)&lds[BOFF(d, nh * 2 + n, ks)];
    };
    auto MM = [&](int mh, int nh) {
        __builtin_amdgcn_s_setprio(1);
        #pragma unroll
        for (int ks = 0; ks < 2; ks++)
            #pragma unroll
            for (int j = 0; j < 4; j++)
                #pragma unroll
                for (int n = 0; n < 2; n++)
                    acc[mh * 4 + j][nh * 2 + n] = __builtin_amdgcn_mfma_f32_16x16x32_bf16(
                        afr[j][ks], bfr[n][ks], acc[mh * 4 + j][nh * 2 + n], 0, 0, 0);
        __builtin_amdgcn_s_setprio(0);
    };

    const int NT = K >> 6, NT2 = K >> 7, NTm1 = NT - 1;

    // ---- prologue: K-tile 0 complete into d0; A_mh0,B_nh1 of K-tile 1 into d1 ----
    SA(0, 0, 0); SB(0, 0, 1); SA(0, 0, 1); SB(0, 0, 0);
    SA(1, 1, 0); SB(1, 1, 1);
    asm volatile("s_waitcnt vmcnt(4)\ns_barrier" ::: "memory");

    #pragma unroll 1
    for (int i = 0; i < NT2; i++) {
        int t1 = 2 * i + 1;
        int t2 = 2 * i + 2; if (t2 > NTm1) t2 = NTm1;
        int t3 = 2 * i + 3; if (t3 > NTm1) t3 = NTm1;

        // ph1 (0,0) d0 | s1: A(d1,mh1)<-t1
        LOAD_A(0, 0); LOAD_B(0, 0);
        SA(t1, 1, 1);
        asm volatile("s_barrier" ::: "memory");
        MM(0, 0);
        asm volatile("s_barrier" ::: "memory");

        // ph2 (0,1) d0 (reuse A) | s2: B(d1,nh0)<-t1
        LOAD_B(0, 1);
        SB(t1, 1, 0);
        asm volatile("s_barrier" ::: "memory");
        MM(0, 1);
        asm volatile("s_barrier" ::: "memory");

        // ph3 (1,1) d0 (reuse B) | s3: A(d0,mh0)<-t2
        LOAD_A(0, 1);
        SA(t2, 0, 0);
        asm volatile("s_barrier" ::: "memory");
        MM(1, 1);
        asm volatile("s_barrier" ::: "memory");

        // ph4 (1,0) d0 (reuse A) | s4: B(d0,nh1)<-t2 | checkpoint
        LOAD_B(0, 0);
        SB(t2, 0, 1);
        asm volatile("s_barrier" ::: "memory");
        MM(1, 0);
        asm volatile("s_waitcnt vmcnt(4)\ns_barrier" ::: "memory");

        // ph5 (0,0) d1 | s5: A(d0,mh1)<-t2
        LOAD_A(1, 0); LOAD_B(1, 0);
        SA(t2, 0, 1);
        asm volatile("s_barrier" ::: "memory");
        MM(0, 0);
        asm volatile("s_barrier" ::: "memory");

        // ph6 (0,1) d1 (reuse A) | s6: B(d0,nh0)<-t2
        LOAD_B(1, 1);
        SB(t2, 0, 0);
        asm volatile("s_barrier" ::: "memory");
        MM(0, 1);
        asm volatile("s_barrier" ::: "memory");

        // ph7 (1,1) d1 (reuse B) | s7: A(d1,mh0)<-t3
        LOAD_A(1, 1);
        SA(t3, 1, 0);
        asm volatile("s_barrier" ::: "memory");
        MM(1, 1);
        asm volatile("s_barrier" ::: "memory");

        // ph8 (1,0) d1 (reuse A) | s8: B(d1,nh1)<-t3 | checkpoint
        LOAD_B(1, 0);
        SB(t3, 1, 1);
        asm volatile("s_barrier" ::: "memory");
        MM(1, 0);
        asm volatile("s_waitcnt vmcnt(4)\ns_barrier" ::: "memory");
    }

    // ---- epilogue ----
    #pragma unroll
    for (int i = 0; i < 8; i++) {
        #pragma unroll
        for (int n = 0; n < 4; n++) {
            int row = m0 + wr * 128 + i * 16 + hi * 4;
            int col = n0 + wc * 64 + n * 16 + l15;
            #pragma unroll
            for (int r = 0; r < 4; r++) {
                float v = acc[i][n][r];
                int rr = row + r;
                if (MODE == 0) {
                    ((float*)C)[(size_t)rr * N + col] = v;
                } else {  // MODE 4
                    if (col < 1024) {
                        int h = col >> 6, dd = col & 63;
                        ((u16*)C)[(((size_t)(rr >> 8) * 16 + h) * 256 + (rr & 255)) * 64 + dd] = f2bf(v);
                    } else if (col < 1152) {
                        u16* lat = (u16*)C + (size_t)16384 * 1024;
                        lat[(size_t)rr * 128 + (col - 1024)] = f2bf(v);
                    }
                }
            }
        }
    }
}

// ---------------- 128x128 single-buffer GEMM (kept for K=128 kv) ----------------
// MODE 3: col<1024 -> K per-head packed; col>=1024 -> V transposed [b][h][d][t]
template <int MODE>
__global__ __launch_bounds__(256) void gemm_bt(const u16* __restrict__ A, const u16* __restrict__ Bt,
                                               void* __restrict__ C, int M, int N, int K) {
    __shared__ u16 As[128 * 32];
    __shared__ u16 Bs[128 * 32];
    const int tid = threadIdx.x;
    const int lane = tid & 63, wid = tid >> 6;
    const int m0 = blockIdx.x * 128, n0 = blockIdx.y * 128;
    const int wr = wid >> 1, wc = wid & 1;

    floatx4 acc[4][4] = {};

    const u16* Ab = A + (size_t)m0 * K;
    const u16* Bb = Bt + (size_t)n0 * K;
    const int p0 = tid, p1 = tid + 256;
    const int ch0 = p0 ^ ((p0 >> 3) & 3);
    const int ch1 = p1 ^ ((p1 >> 3) & 3);
    const size_t off0 = (size_t)(ch0 >> 2) * K + (size_t)(ch0 & 3) * 8;
    const size_t off1 = (size_t)(ch1 >> 2) * K + (size_t)(ch1 & 3) * 8;
    u16* As0 = &As[(wid * 64) * 8];
    u16* As1 = &As[(wid * 64 + 256) * 8];
    u16* Bs0 = &Bs[(wid * 64) * 8];
    u16* Bs1 = &Bs[(wid * 64 + 256) * 8];

    for (int k0 = 0; k0 < K; k0 += 32) {
        gload_lds16(Ab + off0 + k0, As0);
        gload_lds16(Ab + off1 + k0, As1);
        gload_lds16(Bb + off0 + k0, Bs0);
        gload_lds16(Bb + off1 + k0, Bs1);
        __syncthreads();
        short8 af[4], bfr[4];
        #pragma unroll
        for (int i = 0; i < 4; i++) {
            int ac = (wr * 64 + i * 16 + (lane & 15)) * 4 + (lane >> 4);
            ac ^= (ac >> 3) & 3;
            af[i] = *(const short8*)&As[ac * 8];
        }
        #pragma unroll
        for (int j = 0; j < 4; j++) {
            int bc = (wc * 64 + j * 16 + (lane & 15)) * 4 + (lane >> 4);
            bc ^= (bc >> 3) & 3;
            bfr[j] = *(const short8*)&Bs[bc * 8];
        }
        #pragma unroll
        for (int i = 0; i < 4; i++) {
            #pragma unroll
            for (int j = 0; j < 4; j++)
                acc[i][j] = __builtin_amdgcn_mfma_f32_16x16x32_bf16(af[i], bfr[j], acc[i][j], 0, 0, 0);
        }
        __syncthreads();
    }

    const int cr = (lane >> 4) * 4, cc = lane & 15;
    #pragma unroll
    for (int i = 0; i < 4; i++) {
        #pragma unroll
        for (int j = 0; j < 4; j++) {
            int row = m0 + wr * 64 + i * 16 + cr;
            int col = n0 + wc * 64 + j * 16 + cc;
            #pragma unroll
            for (int r = 0; r < 4; r++) {
                float v = acc[i][j][r];
                int rr = row + r;
                if (MODE == 3) {
                    if (col < 1024) {
                        int h = col >> 6, dd = col & 63;
                        ((u16*)C)[(((size_t)(rr >> 8) * 16 + h) * 256 + (rr & 255)) * 64 + dd] = f2bf(v);
                    } else {
                        int d = col - 1024;
                        int h = d >> 6, dd = d & 63;
                        u16* vt = (u16*)C + (size_t)16384 * 1024;
                        vt[(((size_t)(rr >> 8) * 16 + h) * 64 + dd) * 256 + (rr & 255)] = f2bf(v);
                    }
                } else {
                    ((u16*)C)[(size_t)rr * N + col] = f2bf(v);
                }
            }
        }
    }
}

// ---------------- causal attention (32x32x16 structure) ----------------
__global__ __launch_bounds__(256, 3) void attn_kernel(const u16* __restrict__ Qh, const u16* __restrict__ Kh,
                                                      const u16* __restrict__ Vtg, u16* __restrict__ Y) {
    constexpr int T = 256, HD = 1024;
    constexpr int VS = 264;
    __shared__ __align__(16) u16 Vt[64 * VS];

    const int tid = threadIdx.x, lane = tid & 63, wid = tid >> 6;
    const int bh = blockIdx.x;
    const size_t base = (size_t)bh * (T * 64);
    const size_t baseY = (size_t)(bh >> 4) * T * HD + (size_t)(bh & 15) * 64;

    {
        const u16* vsrc = Vtg + base;
        #pragma unroll
        for (int it = 0; it < 8; it++) {
            int idx = tid + it * 256;
            int d = idx >> 5, t0 = (idx & 31) * 8;
            *(short8*)&Vt[d * VS + t0] = *(const short8*)&vsrc[d * 256 + t0];
        }
    }
    __syncthreads();

    const float c_exp = 0.125f * 1.44269504088896f;
    const int qcol = lane & 31, hi2 = lane >> 5;
    const u16* kbase = Kh + base;
    const u16* qbase = Qh + base;
    const u16* vrow0 = &Vt[qcol * VS];
    const u16* vrow1 = &Vt[(qcol + 32) * VS];

    #pragma unroll 1
    for (int half = 0; half < 2; half++) {
        const int qb = half ? (7 - wid) : wid;

        short8 qf[4];
        {
            const u16* qp = &qbase[(size_t)(qb * 32 + qcol) * 64 + hi2 * 8];
            #pragma unroll
            for (int i = 0; i < 4; i++) qf[i] = *(const short8*)&qp[i * 16];
        }

        floatx16 y0 = {0}, y1 = {0};
        float lsum = 0.f;

        for (int kt = 0; kt <= qb; kt++) {
            const u16* kp = &kbase[(size_t)(kt * 32 + qcol) * 64 + hi2 * 8];
            floatx16 s = {0};
            #pragma unroll
            for (int i = 0; i < 4; i++) {
                short8 kf = *(const short8*)&kp[i * 16];
                s = __builtin_amdgcn_mfma_f32_32x32x16_bf16(kf, qf[i], s, 0, 0, 0);
            }

            const bool diag = (kt == qb);
            u32 pk[8];
            #pragma unroll
            for (int r2 = 0; r2 < 8; r2++) {
                const int r0 = 2 * r2;
                const int kr0 = (r0 & 3) + 8 * (r0 >> 2) + 4 * hi2;
                float p0 = exp2f(s[r0] * c_exp);
                float p1 = exp2f(s[r0 + 1] * c_exp);
                if (diag) {
                    if (kr0 > qcol) p0 = 0.f;
                    if (kr0 + 1 > qcol) p1 = 0.f;
                }
                lsum += p0 + p1;
                pk[r2] = (u32)f2bf(p0) | ((u32)f2bf(p1) << 16);
            }

            #pragma unroll
            for (int kh2 = 0; kh2 < 2; kh2++) {
                u32 a0 = pk[kh2 * 4 + 0], a1 = pk[kh2 * 4 + 1];
                u32 b0 = pk[kh2 * 4 + 2], b1 = pk[kh2 * 4 + 3];
                asm volatile("v_permlane32_swap_b32 %0, %1" : "+v"(a0), "+v"(b0));
                asm volatile("v_permlane32_swap_b32 %0, %1" : "+v"(a1), "+v"(b1));
                intx4 w;
                w[0] = (int)a0; w[1] = (int)a1; w[2] = (int)b0; w[3] = (int)b1;
                short8 pa = __builtin_bit_cast(short8, w);
                const int tofs = kt * 32 + kh2 * 16 + hi2 * 8;
                short8 vf0 = *(const short8*)&vrow0[tofs];
                short8 vf1 = *(const short8*)&vrow1[tofs];
                y0 = __builtin_amdgcn_mfma_f32_32x32x16_bf16(pa, vf0, y0, 0, 0, 0);
                y1 = __builtin_amdgcn_mfma_f32_32x32x16_bf16(pa, vf1, y1, 0, 0, 0);
            }
        }

        lsum += __shfl_xor(lsum, 32);
        const float linv = 1.0f / lsum;

        float sc[16];
        #pragma unroll
        for (int r = 0; r < 16; r++)
            sc[r] = __shfl(linv, (r & 3) + 8 * (r >> 2) + 4 * hi2, 64);

        #pragma unroll
        for (int r = 0; r < 16; r++) {
            const int qloc = (r & 3) + 8 * (r >> 2) + 4 * hi2;
            const size_t rowoff = baseY + (size_t)(qb * 32 + qloc) * HD;
            Y[rowoff + qcol]      = f2bf(y0[r] * sc[r]);
            Y[rowoff + 32 + qcol] = f2bf(y1[r] * sc[r]);
        }
    }
}

extern "C" void kernel_launch(void* const* d_in, const int* in_sizes, int n_in,
                              void* d_out, int out_size, void* d_ws, size_t ws_size,
                              hipStream_t stream) {
    const float* x         = (const float*)d_in[0];
    const float* w_kv_down = (const float*)d_in[1];
    const float* w_kv_up   = (const float*)d_in[2];
    const float* w_q       = (const float*)d_in[3];
    const float* w_out     = (const float*)d_in[4];
    float* out = (float*)d_out;

    constexpr int Bb = 64, Tt = 256, Cc = 1024, HD = 1024, R = 128;
    constexpr int M = Bb * Tt;  // 16384

    char* ws = (char*)d_ws;
    auto alloc = [&](size_t bytes) {
        void* p = (void*)ws;
        ws += (bytes + 255) & ~(size_t)255;
        return p;
    };
    u16* xb      = (u16*)alloc((size_t)M * Cc * 2);
    u16* wql_t   = (u16*)alloc((size_t)(HD + 256) * Cc * 2);  // rows 0..1023 Wq^T, 1024..1151 Wkvd^T, rest pad
    u16* wkvu_t  = (u16*)alloc((size_t)2 * HD * R * 2);
    u16* wo_t    = (u16*)alloc((size_t)Cc * HD * 2);
    u16* qh      = (u16*)alloc((size_t)M * HD * 2);      // per-head packed q  [b][h][t][64]
    u16* latentb = (u16*)alloc((size_t)M * R * 2);       // adjacent to qh (MODE 4 epilogue)
    u16* kvb     = (u16*)alloc((size_t)M * 2 * HD * 2);  // kh [b][h][t][64] then vt [b][h][d][t]
    u16* yb      = (u16*)alloc((size_t)M * HD * 2);

    u16* kh  = kvb;
    u16* vtg = kvb + (size_t)M * HD;

    cvt_x<<<2048, 256, 0, stream>>>(x, xb, M * Cc / 4);
    transpose_cvt<<<dim3(HD / 32, Cc / 32), 256, 0, stream>>>(w_q, wql_t, Cc, HD);
    transpose_cvt<<<dim3(R / 32, Cc / 32), 256, 0, stream>>>(w_kv_down, wql_t + (size_t)HD * Cc, Cc, R);
    transpose_cvt<<<dim3(2 * HD / 32, R / 32), 256, 0, stream>>>(w_kv_up, wkvu_t, R, 2 * HD);
    transpose_cvt<<<dim3(Cc / 32, HD / 32), 256, 0, stream>>>(w_out, wo_t, HD, Cc);

    // q + latent fused (N padded to 1280): cols 0..1023 -> qh, 1024..1151 -> latentb
    gemm8p<4><<<dim3((M / 256) * 5), 512, 0, stream>>>(xb, wql_t, qh, M, 1280, Cc, M / 256);
    // kv = latent @ Wkv_up (M x 2048 x 128) -> K per-head packed + V transposed
    gemm_bt<3><<<dim3(M / 128, 2 * HD / 128), 256, 0, stream>>>(latentb, wkvu_t, kvb, M, 2 * HD, R);
    // attention
    attn_kernel<<<Bb * 16, 256, 0, stream>>>(qh, kh, vtg, yb);
    // out = y @ Wout (M x 1024 x 1024), fp32
    gemm8p<0><<<dim3((M / 256) * 4), 512, 0, stream>>>(yb, wo_t, out, M, Cc, HD, M / 256);
}

// Round 10
// 218.910 us; speedup vs baseline: 1.0279x; 1.0279x over previous
//
#include <hip/hip_runtime.h>
#include <hip/hip_bf16.h>
#include <cstdint>
#include <cstddef>

typedef short short8 __attribute__((ext_vector_type(8)));
typedef float floatx4 __attribute__((ext_vector_type(4)));
typedef float floatx16 __attribute__((ext_vector_type(16)));
typedef int intx4 __attribute__((ext_vector_type(4)));
typedef unsigned short u16;
typedef unsigned int u32;

__device__ __forceinline__ u16 f2bf(float f) {
    __hip_bfloat16 h = __float2bfloat16(f);
    return __builtin_bit_cast(u16, h);
}

__device__ __forceinline__ void gload_lds16(const void* g, void* l) {
    __builtin_amdgcn_global_load_lds(
        (const __attribute__((address_space(1))) void*)g,
        (__attribute__((address_space(3))) void*)l, 16, 0, 0);
}

#define SBAR()  __builtin_amdgcn_s_barrier()
#define SCHED() __builtin_amdgcn_sched_barrier(0)

// ---------------- fp32 -> bf16 elementwise ----------------
__global__ __launch_bounds__(256) void cvt_x(const float* __restrict__ in, u16* __restrict__ out, int n4) {
    int stride = gridDim.x * blockDim.x;
    for (int i = blockIdx.x * blockDim.x + threadIdx.x; i < n4; i += stride) {
        float4 v = ((const float4*)in)[i];
        ushort4 o;
        o.x = f2bf(v.x); o.y = f2bf(v.y); o.z = f2bf(v.z); o.w = f2bf(v.w);
        ((ushort4*)out)[i] = o;
    }
}

// ---------------- W[K][N] f32 -> Wt[N][K] bf16 ----------------
__global__ __launch_bounds__(256) void transpose_cvt(const float* __restrict__ W, u16* __restrict__ Wt,
                                                     int K, int N) {
    __shared__ float tile[32][33];
    int n0 = blockIdx.x * 32, k0 = blockIdx.y * 32;
    int tx = threadIdx.x & 31, ty = threadIdx.x >> 5;  // ty 0..7
    #pragma unroll
    for (int i = 0; i < 32; i += 8)
        tile[ty + i][tx] = W[(size_t)(k0 + ty + i) * N + n0 + tx];
    __syncthreads();
    #pragma unroll
    for (int i = 0; i < 32; i += 8)
        Wt[(size_t)(n0 + ty + i) * K + k0 + tx] = f2bf(tile[tx][ty + i]);
}

// ---------------- 256x256 8-phase bf16 GEMM: C = A[M][K] * Bt[N][K]^T ----------------
// Same slot schedule as r9 (correctness-proven). This round's change: barriers are
// __builtin_amdgcn_s_barrier() (NO auto vmcnt drain — the asm "memory"-clobber
// barrier made hipcc emit vmcnt(0) per phase, serializing r7-r9 at the 2-phase
// ceiling), counted vmcnt(4) as bare asm at phases 4/8 only, sched_barrier(0)
// fences at phase boundaries (rule #18). Decomposition nx-fastest so wgs sharing
// an A-panel are XCD-adjacent (FETCH was 2.5x ideal with mx-fastest).
template <int MODE>
__global__ __launch_bounds__(512, 2) void gemm8p(const u16* __restrict__ A, const u16* __restrict__ Bt,
                                                 void* __restrict__ C, int M, int N, int K, int nwgy) {
    __shared__ __align__(16) u16 lds[65536];  // 128 KB
    const int tid = threadIdx.x;
    const int lane = tid & 63, wid = tid >> 6;
    const int wr = wid >> 2, wc = wid & 3;
    const int l15 = lane & 15, hi = lane >> 4;

    // bijective XCD swizzle (nwg % 8 == 0), then nx-fastest decomposition
    const int nwg = gridDim.x;
    const int qch = nwg >> 3;
    const int wg = (blockIdx.x & 7) * qch + (blockIdx.x >> 3);
    const int mx = wg / nwgy, nx = wg % nwgy;
    const int m0 = mx * 256, n0 = nx * 256;

    const u16* Ab = A + (size_t)m0 * K;
    const u16* Bb = Bt + (size_t)n0 * K;

    // ---- staging (source carries the involution; LDS dest is linear per load) ----
    auto SA = [&](int kt, int d, int mh) {  // A unit mh -> dbuf d
        u16* base = &lds[d * 32768];
        #pragma unroll
        for (int l = 0; l < 2; l++) {
            int p = l * 1024 + mh * 512 + tid;           // position chunk
            int c = p ^ ((p >> 3) & 7);                  // source chunk (involution)
            const u16* src = Ab + (size_t)(c >> 3) * K + (c & 7) * 8 + kt * 64;
            gload_lds16(src, base + (l * 1024 + mh * 512 + wid * 64) * 8);
        }
    };
    auto SB = [&](int kt, int d, int nh) {  // B unit nh -> dbuf d
        u16* base = &lds[d * 32768 + 16384];
        #pragma unroll
        for (int l = 0; l < 2; l++) {
            int wcb = l * 2 + (wid >> 2);                // wave-uniform
            int p = wcb * 512 + nh * 256 + (wid & 3) * 64 + lane;
            int c = p ^ ((p >> 3) & 7);
            const u16* src = Bb + (size_t)(c >> 3) * K + (c & 7) * 8 + kt * 64;
            gload_lds16(src, base + (wcb * 512 + nh * 256 + (wid & 3) * 64) * 8);
        }
    };

    // ---- fragment read offsets (q = c ^ (row&7), c = row*8 + ks*4 + hi) ----
    auto AOFF = [&](int d, int mt, int ks) {
        int row = wr * 128 + mt * 16 + l15;
        int q = (row * 8 + ks * 4 + hi) ^ (row & 7);
        return d * 32768 + q * 8;
    };
    auto BOFF = [&](int d, int nt, int ks) {
        int row = wc * 64 + nt * 16 + l15;
        int q = (row * 8 + ks * 4 + hi) ^ (row & 7);
        return d * 32768 + 16384 + q * 8;
    };

    short8 afr[4][2], bfr[2][2];
    floatx4 acc[8][4] = {};

    auto LOAD_A = [&](int d, int mh) {
        #pragma unroll
        for (int j = 0; j < 4; j++)
            #pragma unroll
            for (int ks = 0; ks < 2; ks++)
                afr[j][ks] = *(const short8*)&lds[AOFF(d, mh * 4 + j, ks)];
    };
    auto LOAD_B = [&](int d, int nh) {
        #pragma unroll
        for (int n = 0; n < 2; n++)
            #pragma unroll
            for (int ks = 0; ks < 2; ks++)
                bfr[n][ks] = *(const short8*)&lds[BOFF(d, nh * 2 + n, ks)];
    };
    auto MM = [&](int mh, int nh) {
        __builtin_amdgcn_s_setprio(1);
        #pragma unroll
        for (int ks = 0; ks < 2; ks++)
            #pragma unroll
            for (int j = 0; j < 4; j++)
                #pragma unroll
                for (int n = 0; n < 2; n++)
                    acc[mh * 4 + j][nh * 2 + n] = __builtin_amdgcn_mfma_f32_16x16x32_bf16(
                        afr[j][ks], bfr[n][ks], acc[mh * 4 + j][nh * 2 + n], 0, 0, 0);
        __builtin_amdgcn_s_setprio(0);
    };

    const int NT = K >> 6, NT2 = K >> 7, NTm1 = NT - 1;

    // ---- prologue: K-tile 0 complete into d0; A_mh0,B_nh1 of K-tile 1 into d1 ----
    SA(0, 0, 0); SB(0, 0, 1); SA(0, 0, 1); SB(0, 0, 0);
    SA(1, 1, 0); SB(1, 1, 1);
    SCHED();
    asm volatile("s_waitcnt vmcnt(4)");
    SCHED(); SBAR(); SCHED();

    #pragma unroll 1
    for (int i = 0; i < NT2; i++) {
        int t1 = 2 * i + 1;
        int t2 = 2 * i + 2; if (t2 > NTm1) t2 = NTm1;
        int t3 = 2 * i + 3; if (t3 > NTm1) t3 = NTm1;

        // ph1 (0,0) d0 | s1: A(d1,mh1)<-t1
        LOAD_A(0, 0); LOAD_B(0, 0);
        SA(t1, 1, 1);
        SCHED(); SBAR(); SCHED();
        MM(0, 0);
        SCHED(); SBAR(); SCHED();

        // ph2 (0,1) d0 (reuse A) | s2: B(d1,nh0)<-t1
        LOAD_B(0, 1);
        SB(t1, 1, 0);
        SCHED(); SBAR(); SCHED();
        MM(0, 1);
        SCHED(); SBAR(); SCHED();

        // ph3 (1,1) d0 (reuse B) | s3: A(d0,mh0)<-t2
        LOAD_A(0, 1);
        SA(t2, 0, 0);
        SCHED(); SBAR(); SCHED();
        MM(1, 1);
        SCHED(); SBAR(); SCHED();

        // ph4 (1,0) d0 (reuse A) | s4: B(d0,nh1)<-t2 | checkpoint vmcnt(4)
        LOAD_B(0, 0);
        SB(t2, 0, 1);
        SCHED(); SBAR(); SCHED();
        MM(1, 0);
        SCHED();
        asm volatile("s_waitcnt vmcnt(4)");
        SCHED(); SBAR(); SCHED();

        // ph5 (0,0) d1 | s5: A(d0,mh1)<-t2
        LOAD_A(1, 0); LOAD_B(1, 0);
        SA(t2, 0, 1);
        SCHED(); SBAR(); SCHED();
        MM(0, 0);
        SCHED(); SBAR(); SCHED();

        // ph6 (0,1) d1 (reuse A) | s6: B(d0,nh0)<-t2
        LOAD_B(1, 1);
        SB(t2, 0, 0);
        SCHED(); SBAR(); SCHED();
        MM(0, 1);
        SCHED(); SBAR(); SCHED();

        // ph7 (1,1) d1 (reuse B) | s7: A(d1,mh0)<-t3
        LOAD_A(1, 1);
        SA(t3, 1, 0);
        SCHED(); SBAR(); SCHED();
        MM(1, 1);
        SCHED(); SBAR(); SCHED();

        // ph8 (1,0) d1 (reuse A) | s8: B(d1,nh1)<-t3 | checkpoint vmcnt(4)
        LOAD_B(1, 0);
        SB(t3, 1, 1);
        SCHED(); SBAR(); SCHED();
        MM(1, 0);
        SCHED();
        asm volatile("s_waitcnt vmcnt(4)");
        SCHED(); SBAR(); SCHED();
    }

    // ---- epilogue ----
    #pragma unroll
    for (int i = 0; i < 8; i++) {
        #pragma unroll
        for (int n = 0; n < 4; n++) {
            int row = m0 + wr * 128 + i * 16 + hi * 4;
            int col = n0 + wc * 64 + n * 16 + l15;
            #pragma unroll
            for (int r = 0; r < 4; r++) {
                float v = acc[i][n][r];
                int rr = row + r;
                if (MODE == 0) {
                    ((float*)C)[(size_t)rr * N + col] = v;
                } else {  // MODE 4
                    if (col < 1024) {
                        int h = col >> 6, dd = col & 63;
                        ((u16*)C)[(((size_t)(rr >> 8) * 16 + h) * 256 + (rr & 255)) * 64 + dd] = f2bf(v);
                    } else if (col < 1152) {
                        u16* lat = (u16*)C + (size_t)16384 * 1024;
                        lat[(size_t)rr * 128 + (col - 1024)] = f2bf(v);
                    }
                }
            }
        }
    }
}

// ---------------- 128x128 single-buffer GEMM (kept for K=128 kv) ----------------
// MODE 3: col<1024 -> K per-head packed; col>=1024 -> V transposed [b][h][d][t]
template <int MODE>
__global__ __launch_bounds__(256) void gemm_bt(const u16* __restrict__ A, const u16* __restrict__ Bt,
                                               void* __restrict__ C, int M, int N, int K) {
    __shared__ u16 As[128 * 32];
    __shared__ u16 Bs[128 * 32];
    const int tid = threadIdx.x;
    const int lane = tid & 63, wid = tid >> 6;
    const int m0 = blockIdx.x * 128, n0 = blockIdx.y * 128;
    const int wr = wid >> 1, wc = wid & 1;

    floatx4 acc[4][4] = {};

    const u16* Ab = A + (size_t)m0 * K;
    const u16* Bb = Bt + (size_t)n0 * K;
    const int p0 = tid, p1 = tid + 256;
    const int ch0 = p0 ^ ((p0 >> 3) & 3);
    const int ch1 = p1 ^ ((p1 >> 3) & 3);
    const size_t off0 = (size_t)(ch0 >> 2) * K + (size_t)(ch0 & 3) * 8;
    const size_t off1 = (size_t)(ch1 >> 2) * K + (size_t)(ch1 & 3) * 8;
    u16* As0 = &As[(wid * 64) * 8];
    u16* As1 = &As[(wid * 64 + 256) * 8];
    u16* Bs0 = &Bs[(wid * 64) * 8];
    u16* Bs1 = &Bs[(wid * 64 + 256) * 8];

    for (int k0 = 0; k0 < K; k0 += 32) {
        gload_lds16(Ab + off0 + k0, As0);
        gload_lds16(Ab + off1 + k0, As1);
        gload_lds16(Bb + off0 + k0, Bs0);
        gload_lds16(Bb + off1 + k0, Bs1);
        __syncthreads();
        short8 af[4], bfr[4];
        #pragma unroll
        for (int i = 0; i < 4; i++) {
            int ac = (wr * 64 + i * 16 + (lane & 15)) * 4 + (lane >> 4);
            ac ^= (ac >> 3) & 3;
            af[i] = *(const short8*)&As[ac * 8];
        }
        #pragma unroll
        for (int j = 0; j < 4; j++) {
            int bc = (wc * 64 + j * 16 + (lane & 15)) * 4 + (lane >> 4);
            bc ^= (bc >> 3) & 3;
            bfr[j] = *(const short8*)&Bs[bc * 8];
        }
        #pragma unroll
        for (int i = 0; i < 4; i++) {
            #pragma unroll
            for (int j = 0; j < 4; j++)
                acc[i][j] = __builtin_amdgcn_mfma_f32_16x16x32_bf16(af[i], bfr[j], acc[i][j], 0, 0, 0);
        }
        __syncthreads();
    }

    const int cr = (lane >> 4) * 4, cc = lane & 15;
    #pragma unroll
    for (int i = 0; i < 4; i++) {
        #pragma unroll
        for (int j = 0; j < 4; j++) {
            int row = m0 + wr * 64 + i * 16 + cr;
            int col = n0 + wc * 64 + j * 16 + cc;
            #pragma unroll
            for (int r = 0; r < 4; r++) {
                float v = acc[i][j][r];
                int rr = row + r;
                if (MODE == 3) {
                    if (col < 1024) {
                        int h = col >> 6, dd = col & 63;
                        ((u16*)C)[(((size_t)(rr >> 8) * 16 + h) * 256 + (rr & 255)) * 64 + dd] = f2bf(v);
                    } else {
                        int d = col - 1024;
                        int h = d >> 6, dd = d & 63;
                        u16* vt = (u16*)C + (size_t)16384 * 1024;
                        vt[(((size_t)(rr >> 8) * 16 + h) * 64 + dd) * 256 + (rr & 255)] = f2bf(v);
                    }
                } else {
                    ((u16*)C)[(size_t)rr * N + col] = f2bf(v);
                }
            }
        }
    }
}

// ---------------- causal attention (32x32x16 structure) ----------------
__global__ __launch_bounds__(256, 3) void attn_kernel(const u16* __restrict__ Qh, const u16* __restrict__ Kh,
                                                      const u16* __restrict__ Vtg, u16* __restrict__ Y) {
    constexpr int T = 256, HD = 1024;
    constexpr int VS = 264;
    __shared__ __align__(16) u16 Vt[64 * VS];

    const int tid = threadIdx.x, lane = tid & 63, wid = tid >> 6;
    const int bh = blockIdx.x;
    const size_t base = (size_t)bh * (T * 64);
    const size_t baseY = (size_t)(bh >> 4) * T * HD + (size_t)(bh & 15) * 64;

    {
        const u16* vsrc = Vtg + base;
        #pragma unroll
        for (int it = 0; it < 8; it++) {
            int idx = tid + it * 256;
            int d = idx >> 5, t0 = (idx & 31) * 8;
            *(short8*)&Vt[d * VS + t0] = *(const short8*)&vsrc[d * 256 + t0];
        }
    }
    __syncthreads();

    const float c_exp = 0.125f * 1.44269504088896f;
    const int qcol = lane & 31, hi2 = lane >> 5;
    const u16* kbase = Kh + base;
    const u16* qbase = Qh + base;
    const u16* vrow0 = &Vt[qcol * VS];
    const u16* vrow1 = &Vt[(qcol + 32) * VS];

    #pragma unroll 1
    for (int half = 0; half < 2; half++) {
        const int qb = half ? (7 - wid) : wid;

        short8 qf[4];
        {
            const u16* qp = &qbase[(size_t)(qb * 32 + qcol) * 64 + hi2 * 8];
            #pragma unroll
            for (int i = 0; i < 4; i++) qf[i] = *(const short8*)&qp[i * 16];
        }

        floatx16 y0 = {0}, y1 = {0};
        float lsum = 0.f;

        for (int kt = 0; kt <= qb; kt++) {
            const u16* kp = &kbase[(size_t)(kt * 32 + qcol) * 64 + hi2 * 8];
            floatx16 s = {0};
            #pragma unroll
            for (int i = 0; i < 4; i++) {
                short8 kf = *(const short8*)&kp[i * 16];
                s = __builtin_amdgcn_mfma_f32_32x32x16_bf16(kf, qf[i], s, 0, 0, 0);
            }

            const bool diag = (kt == qb);
            u32 pk[8];
            #pragma unroll
            for (int r2 = 0; r2 < 8; r2++) {
                const int r0 = 2 * r2;
                const int kr0 = (r0 & 3) + 8 * (r0 >> 2) + 4 * hi2;
                float p0 = exp2f(s[r0] * c_exp);
                float p1 = exp2f(s[r0 + 1] * c_exp);
                if (diag) {
                    if (kr0 > qcol) p0 = 0.f;
                    if (kr0 + 1 > qcol) p1 = 0.f;
                }
                lsum += p0 + p1;
                pk[r2] = (u32)f2bf(p0) | ((u32)f2bf(p1) << 16);
            }

            #pragma unroll
            for (int kh2 = 0; kh2 < 2; kh2++) {
                u32 a0 = pk[kh2 * 4 + 0], a1 = pk[kh2 * 4 + 1];
                u32 b0 = pk[kh2 * 4 + 2], b1 = pk[kh2 * 4 + 3];
                asm volatile("v_permlane32_swap_b32 %0, %1" : "+v"(a0), "+v"(b0));
                asm volatile("v_permlane32_swap_b32 %0, %1" : "+v"(a1), "+v"(b1));
                intx4 w;
                w[0] = (int)a0; w[1] = (int)a1; w[2] = (int)b0; w[3] = (int)b1;
                short8 pa = __builtin_bit_cast(short8, w);
                const int tofs = kt * 32 + kh2 * 16 + hi2 * 8;
                short8 vf0 = *(const short8*)&vrow0[tofs];
                short8 vf1 = *(const short8*)&vrow1[tofs];
                y0 = __builtin_amdgcn_mfma_f32_32x32x16_bf16(pa, vf0, y0, 0, 0, 0);
                y1 = __builtin_amdgcn_mfma_f32_32x32x16_bf16(pa, vf1, y1, 0, 0, 0);
            }
        }

        lsum += __shfl_xor(lsum, 32);
        const float linv = 1.0f / lsum;

        float sc[16];
        #pragma unroll
        for (int r = 0; r < 16; r++)
            sc[r] = __shfl(linv, (r & 3) + 8 * (r >> 2) + 4 * hi2, 64);

        #pragma unroll
        for (int r = 0; r < 16; r++) {
            const int qloc = (r & 3) + 8 * (r >> 2) + 4 * hi2;
            const size_t rowoff = baseY + (size_t)(qb * 32 + qloc) * HD;
            Y[rowoff + qcol]      = f2bf(y0[r] * sc[r]);
            Y[rowoff + 32 + qcol] = f2bf(y1[r] * sc[r]);
        }
    }
}

extern "C" void kernel_launch(void* const* d_in, const int* in_sizes, int n_in,
                              void* d_out, int out_size, void* d_ws, size_t ws_size,
                              hipStream_t stream) {
    const float* x         = (const float*)d_in[0];
    const float* w_kv_down = (const float*)d_in[1];
    const float* w_kv_up   = (const float*)d_in[2];
    const float* w_q       = (const float*)d_in[3];
    const float* w_out     = (const float*)d_in[4];
    float* out = (float*)d_out;

    constexpr int Bb = 64, Tt = 256, Cc = 1024, HD = 1024, R = 128;
    constexpr int M = Bb * Tt;  // 16384

    char* ws = (char*)d_ws;
    auto alloc = [&](size_t bytes) {
        void* p = (void*)ws;
        ws += (bytes + 255) & ~(size_t)255;
        return p;
    };
    u16* xb      = (u16*)alloc((size_t)M * Cc * 2);
    u16* wql_t   = (u16*)alloc((size_t)(HD + 256) * Cc * 2);  // rows 0..1023 Wq^T, 1024..1151 Wkvd^T, rest pad
    u16* wkvu_t  = (u16*)alloc((size_t)2 * HD * R * 2);
    u16* wo_t    = (u16*)alloc((size_t)Cc * HD * 2);
    u16* qh      = (u16*)alloc((size_t)M * HD * 2);      // per-head packed q  [b][h][t][64]
    u16* latentb = (u16*)alloc((size_t)M * R * 2);       // adjacent to qh (MODE 4 epilogue)
    u16* kvb     = (u16*)alloc((size_t)M * 2 * HD * 2);  // kh [b][h][t][64] then vt [b][h][d][t]
    u16* yb      = (u16*)alloc((size_t)M * HD * 2);

    u16* kh  = kvb;
    u16* vtg = kvb + (size_t)M * HD;

    cvt_x<<<2048, 256, 0, stream>>>(x, xb, M * Cc / 4);
    transpose_cvt<<<dim3(HD / 32, Cc / 32), 256, 0, stream>>>(w_q, wql_t, Cc, HD);
    transpose_cvt<<<dim3(R / 32, Cc / 32), 256, 0, stream>>>(w_kv_down, wql_t + (size_t)HD * Cc, Cc, R);
    transpose_cvt<<<dim3(2 * HD / 32, R / 32), 256, 0, stream>>>(w_kv_up, wkvu_t, R, 2 * HD);
    transpose_cvt<<<dim3(Cc / 32, HD / 32), 256, 0, stream>>>(w_out, wo_t, HD, Cc);

    // q + latent fused (N padded to 1280): cols 0..1023 -> qh, 1024..1151 -> latentb
    gemm8p<4><<<dim3((M / 256) * 5), 512, 0, stream>>>(xb, wql_t, qh, M, 1280, Cc, 5);
    // kv = latent @ Wkv_up (M x 2048 x 128) -> K per-head packed + V transposed
    gemm_bt<3><<<dim3(M / 128, 2 * HD / 128), 256, 0, stream>>>(latentb, wkvu_t, kvb, M, 2 * HD, R);
    // attention
    attn_kernel<<<Bb * 16, 256, 0, stream>>>(qh, kh, vtg, yb);
    // out = y @ Wout (M x 1024 x 1024), fp32
    gemm8p<0><<<dim3((M / 256) * 4), 512, 0, stream>>>(yb, wo_t, out, M, Cc, HD, 4);
}

// Round 11
// 195.587 us; speedup vs baseline: 1.1505x; 1.1192x over previous
//
#include <hip/hip_runtime.h>
#include <hip/hip_bf16.h>
#include <cstdint>
#include <cstddef>

typedef short short8 __attribute__((ext_vector_type(8)));
typedef float floatx4 __attribute__((ext_vector_type(4)));
typedef float floatx16 __attribute__((ext_vector_type(16)));
typedef int intx4 __attribute__((ext_vector_type(4)));
typedef unsigned short u16;
typedef unsigned int u32;

__device__ __forceinline__ u16 f2bf(float f) {
    __hip_bfloat16 h = __float2bfloat16(f);
    return __builtin_bit_cast(u16, h);
}

__device__ __forceinline__ void gload_lds16(const void* g, void* l) {
    __builtin_amdgcn_global_load_lds(
        (const __attribute__((address_space(1))) void*)g,
        (__attribute__((address_space(3))) void*)l, 16, 0, 0);
}

// ---------------- fused prep: x f32->bf16 + all weight transposes ----------------
// blocks [0,2048): cvt_x grid-stride; [2048,3072): wq^T; [3072,3200): wkvd^T (rows
// 1024..1151 of wql_t); [3200,3456): wkvu^T; [3456,4480): wo^T.
__global__ __launch_bounds__(256) void prep(const float* __restrict__ x, u16* __restrict__ xb,
                                            const float* __restrict__ wq, const float* __restrict__ wkvd,
                                            const float* __restrict__ wkvu, const float* __restrict__ wo,
                                            u16* __restrict__ wql_t, u16* __restrict__ wkvu_t,
                                            u16* __restrict__ wo_t) {
    const int b = blockIdx.x;
    if (b < 2048) {
        const int n4 = 16384 * 1024 / 4;
        for (int i = b * 256 + threadIdx.x; i < n4; i += 2048 * 256) {
            float4 v = ((const float4*)x)[i];
            ushort4 o;
            o.x = f2bf(v.x); o.y = f2bf(v.y); o.z = f2bf(v.z); o.w = f2bf(v.w);
            ((ushort4*)xb)[i] = o;
        }
    } else {
        __shared__ float tile[32][33];
        const float* W; u16* Wt; int K, N, lb;
        if (b < 3072)      { W = wq;   Wt = wql_t;                       K = 1024; N = 1024; lb = b - 2048; }
        else if (b < 3200) { W = wkvd; Wt = wql_t + (size_t)1024 * 1024; K = 1024; N = 128;  lb = b - 3072; }
        else if (b < 3456) { W = wkvu; Wt = wkvu_t;                      K = 128;  N = 2048; lb = b - 3200; }
        else               { W = wo;   Wt = wo_t;                        K = 1024; N = 1024; lb = b - 3456; }
        const int nb = N / 32;
        const int n0 = (lb % nb) * 32, k0 = (lb / nb) * 32;
        const int tx = threadIdx.x & 31, ty = threadIdx.x >> 5;
        #pragma unroll
        for (int i = 0; i < 32; i += 8)
            tile[ty + i][tx] = W[(size_t)(k0 + ty + i) * N + n0 + tx];
        __syncthreads();
        #pragma unroll
        for (int i = 0; i < 32; i += 8)
            Wt[(size_t)(n0 + ty + i) * K + k0 + tx] = f2bf(tile[tx][ty + i]);
    }
}

// ---------------- 128x128 BK=64 bf16 GEMM: C = A[M][K] * Bt[N][K]^T ----------------
// 2-phase structure (m97-class), 256 threads / 4 waves (2x2), wave tile 64x64,
// single 32KB LDS buffer, chunk-XOR involution (p = c ^ ((c>>3)&7); 0-conflict,
// measured r6-r10). BK=64 halves the per-K vmcnt-drain count vs BK=32; occupancy
// (launch_bounds(256,4) -> ~4 blocks/CU) provides cross-block MFMA cover during
// drains (m114 mechanism — what m97's 912 TF actually relied on).
// Grid 1-D, chunked-bijective XCD swizzle (nwg%8==0), n-fastest: each XCD owns
// whole A-panels (panel's 8-9 column-blocks run on one XCD -> L2 hits).
// MODE: 0 = f32 [M][N]; 4 = col<1024 -> per-head packed q [b][h][t][64],
//       col>=1024 -> latent [M][128] appended after q (N=1152, no padding).
template <int MODE>
__global__ __launch_bounds__(256, 4) void gemm_bt64(const u16* __restrict__ A, const u16* __restrict__ Bt,
                                                    void* __restrict__ C, int M, int N, int K, int ncols) {
    __shared__ __align__(16) u16 As[128 * 64];
    __shared__ __align__(16) u16 Bs[128 * 64];
    const int tid = threadIdx.x;
    const int lane = tid & 63, wid = tid >> 6;
    const int wr = wid >> 1, wc = wid & 1;
    const int l15 = lane & 15, hi = lane >> 4;

    const int nwg = gridDim.x, q8 = nwg >> 3;
    const int wg = (blockIdx.x & 7) * q8 + (blockIdx.x >> 3);
    const int m0 = (wg / ncols) * 128, n0 = (wg % ncols) * 128;

    const u16* Ab = A + (size_t)m0 * K;
    const u16* Bb = Bt + (size_t)n0 * K;

    // staging: LDS pos-chunk p holds source chunk c = p ^ ((p>>3)&7) (involution)
    u32 soff[4];
    #pragma unroll
    for (int l = 0; l < 4; l++) {
        int p = l * 256 + tid, c = p ^ ((p >> 3) & 7);
        soff[l] = (u32)((c >> 3) * K + (c & 7) * 8);
    }

    // fragment offsets: row's chunk c = row*8 + ks*4 + hi -> pos p = c ^ (row&7)
    int afo[4][2], bfo[4][2];
    #pragma unroll
    for (int i = 0; i < 4; i++) {
        #pragma unroll
        for (int ks = 0; ks < 2; ks++) {
            int ra = wr * 64 + i * 16 + l15;
            afo[i][ks] = ((ra * 8 + ks * 4 + hi) ^ (ra & 7)) * 8;
            int rb = wc * 64 + i * 16 + l15;
            bfo[i][ks] = ((rb * 8 + ks * 4 + hi) ^ (rb & 7)) * 8;
        }
    }

    floatx4 acc[4][4] = {};

    for (int k0 = 0; k0 < K; k0 += 64) {
        #pragma unroll
        for (int l = 0; l < 4; l++)
            gload_lds16(Ab + soff[l] + k0, As + (size_t)(l * 256 + wid * 64) * 8);
        #pragma unroll
        for (int l = 0; l < 4; l++)
            gload_lds16(Bb + soff[l] + k0, Bs + (size_t)(l * 256 + wid * 64) * 8);
        __syncthreads();
        #pragma unroll
        for (int ks = 0; ks < 2; ks++) {
            short8 af[4], bf[4];
            #pragma unroll
            for (int i = 0; i < 4; i++) af[i] = *(const short8*)&As[afo[i][ks]];
            #pragma unroll
            for (int j = 0; j < 4; j++) bf[j] = *(const short8*)&Bs[bfo[j][ks]];
            #pragma unroll
            for (int i = 0; i < 4; i++) {
                #pragma unroll
                for (int j = 0; j < 4; j++)
                    acc[i][j] = __builtin_amdgcn_mfma_f32_16x16x32_bf16(af[i], bf[j], acc[i][j], 0, 0, 0);
            }
        }
        __syncthreads();
    }

    const int cr = hi * 4, cc = l15;
    #pragma unroll
    for (int i = 0; i < 4; i++) {
        #pragma unroll
        for (int j = 0; j < 4; j++) {
            int row = m0 + wr * 64 + i * 16 + cr;
            int col = n0 + wc * 64 + j * 16 + cc;
            #pragma unroll
            for (int r = 0; r < 4; r++) {
                float v = acc[i][j][r];
                int rr = row + r;
                if (MODE == 0) {
                    ((float*)C)[(size_t)rr * N + col] = v;
                } else {  // MODE 4
                    if (col < 1024) {
                        int h = col >> 6, dd = col & 63;
                        ((u16*)C)[(((size_t)(rr >> 8) * 16 + h) * 256 + (rr & 255)) * 64 + dd] = f2bf(v);
                    } else {
                        u16* lat = (u16*)C + (size_t)16384 * 1024;
                        lat[(size_t)rr * 128 + (col - 1024)] = f2bf(v);
                    }
                }
            }
        }
    }
}

// ---------------- 128x128 single-buffer GEMM (K=128 kv) ----------------
// MODE 3: col<1024 -> K per-head packed; col>=1024 -> V transposed [b][h][d][t]
template <int MODE>
__global__ __launch_bounds__(256) void gemm_bt(const u16* __restrict__ A, const u16* __restrict__ Bt,
                                               void* __restrict__ C, int M, int N, int K) {
    __shared__ u16 As[128 * 32];
    __shared__ u16 Bs[128 * 32];
    const int tid = threadIdx.x;
    const int lane = tid & 63, wid = tid >> 6;
    const int m0 = blockIdx.x * 128, n0 = blockIdx.y * 128;
    const int wr = wid >> 1, wc = wid & 1;

    floatx4 acc[4][4] = {};

    const u16* Ab = A + (size_t)m0 * K;
    const u16* Bb = Bt + (size_t)n0 * K;
    const int p0 = tid, p1 = tid + 256;
    const int ch0 = p0 ^ ((p0 >> 3) & 3);
    const int ch1 = p1 ^ ((p1 >> 3) & 3);
    const size_t off0 = (size_t)(ch0 >> 2) * K + (size_t)(ch0 & 3) * 8;
    const size_t off1 = (size_t)(ch1 >> 2) * K + (size_t)(ch1 & 3) * 8;
    u16* As0 = &As[(wid * 64) * 8];
    u16* As1 = &As[(wid * 64 + 256) * 8];
    u16* Bs0 = &Bs[(wid * 64) * 8];
    u16* Bs1 = &Bs[(wid * 64 + 256) * 8];

    for (int k0 = 0; k0 < K; k0 += 32) {
        gload_lds16(Ab + off0 + k0, As0);
        gload_lds16(Ab + off1 + k0, As1);
        gload_lds16(Bb + off0 + k0, Bs0);
        gload_lds16(Bb + off1 + k0, Bs1);
        __syncthreads();
        short8 af[4], bfr[4];
        #pragma unroll
        for (int i = 0; i < 4; i++) {
            int ac = (wr * 64 + i * 16 + (lane & 15)) * 4 + (lane >> 4);
            ac ^= (ac >> 3) & 3;
            af[i] = *(const short8*)&As[ac * 8];
        }
        #pragma unroll
        for (int j = 0; j < 4; j++) {
            int bc = (wc * 64 + j * 16 + (lane & 15)) * 4 + (lane >> 4);
            bc ^= (bc >> 3) & 3;
            bfr[j] = *(const short8*)&Bs[bc * 8];
        }
        #pragma unroll
        for (int i = 0; i < 4; i++) {
            #pragma unroll
            for (int j = 0; j < 4; j++)
                acc[i][j] = __builtin_amdgcn_mfma_f32_16x16x32_bf16(af[i], bfr[j], acc[i][j], 0, 0, 0);
        }
        __syncthreads();
    }

    const int cr = (lane >> 4) * 4, cc = lane & 15;
    #pragma unroll
    for (int i = 0; i < 4; i++) {
        #pragma unroll
        for (int j = 0; j < 4; j++) {
            int row = m0 + wr * 64 + i * 16 + cr;
            int col = n0 + wc * 64 + j * 16 + cc;
            #pragma unroll
            for (int r = 0; r < 4; r++) {
                float v = acc[i][j][r];
                int rr = row + r;
                if (MODE == 3) {
                    if (col < 1024) {
                        int h = col >> 6, dd = col & 63;
                        ((u16*)C)[(((size_t)(rr >> 8) * 16 + h) * 256 + (rr & 255)) * 64 + dd] = f2bf(v);
                    } else {
                        int d = col - 1024;
                        int h = d >> 6, dd = d & 63;
                        u16* vt = (u16*)C + (size_t)16384 * 1024;
                        vt[(((size_t)(rr >> 8) * 16 + h) * 64 + dd) * 256 + (rr & 255)] = f2bf(v);
                    }
                } else {
                    ((u16*)C)[(size_t)rr * N + col] = f2bf(v);
                }
            }
        }
    }
}

// ---------------- causal attention (32x32x16 structure) ----------------
__global__ __launch_bounds__(256, 3) void attn_kernel(const u16* __restrict__ Qh, const u16* __restrict__ Kh,
                                                      const u16* __restrict__ Vtg, u16* __restrict__ Y) {
    constexpr int T = 256, HD = 1024;
    constexpr int VS = 264;
    __shared__ __align__(16) u16 Vt[64 * VS];

    const int tid = threadIdx.x, lane = tid & 63, wid = tid >> 6;
    const int bh = blockIdx.x;
    const size_t base = (size_t)bh * (T * 64);
    const size_t baseY = (size_t)(bh >> 4) * T * HD + (size_t)(bh & 15) * 64;

    {
        const u16* vsrc = Vtg + base;
        #pragma unroll
        for (int it = 0; it < 8; it++) {
            int idx = tid + it * 256;
            int d = idx >> 5, t0 = (idx & 31) * 8;
            *(short8*)&Vt[d * VS + t0] = *(const short8*)&vsrc[d * 256 + t0];
        }
    }
    __syncthreads();

    const float c_exp = 0.125f * 1.44269504088896f;
    const int qcol = lane & 31, hi2 = lane >> 5;
    const u16* kbase = Kh + base;
    const u16* qbase = Qh + base;
    const u16* vrow0 = &Vt[qcol * VS];
    const u16* vrow1 = &Vt[(qcol + 32) * VS];

    #pragma unroll 1
    for (int half = 0; half < 2; half++) {
        const int qb = half ? (7 - wid) : wid;

        short8 qf[4];
        {
            const u16* qp = &qbase[(size_t)(qb * 32 + qcol) * 64 + hi2 * 8];
            #pragma unroll
            for (int i = 0; i < 4; i++) qf[i] = *(const short8*)&qp[i * 16];
        }

        floatx16 y0 = {0}, y1 = {0};
        float lsum = 0.f;

        for (int kt = 0; kt <= qb; kt++) {
            const u16* kp = &kbase[(size_t)(kt * 32 + qcol) * 64 + hi2 * 8];
            floatx16 s = {0};
            #pragma unroll
            for (int i = 0; i < 4; i++) {
                short8 kf = *(const short8*)&kp[i * 16];
                s = __builtin_amdgcn_mfma_f32_32x32x16_bf16(kf, qf[i], s, 0, 0, 0);
            }

            const bool diag = (kt == qb);
            u32 pk[8];
            #pragma unroll
            for (int r2 = 0; r2 < 8; r2++) {
                const int r0 = 2 * r2;
                const int kr0 = (r0 & 3) + 8 * (r0 >> 2) + 4 * hi2;
                float p0 = exp2f(s[r0] * c_exp);
                float p1 = exp2f(s[r0 + 1] * c_exp);
                if (diag) {
                    if (kr0 > qcol) p0 = 0.f;
                    if (kr0 + 1 > qcol) p1 = 0.f;
                }
                lsum += p0 + p1;
                pk[r2] = (u32)f2bf(p0) | ((u32)f2bf(p1) << 16);
            }

            #pragma unroll
            for (int kh2 = 0; kh2 < 2; kh2++) {
                u32 a0 = pk[kh2 * 4 + 0], a1 = pk[kh2 * 4 + 1];
                u32 b0 = pk[kh2 * 4 + 2], b1 = pk[kh2 * 4 + 3];
                asm volatile("v_permlane32_swap_b32 %0, %1" : "+v"(a0), "+v"(b0));
                asm volatile("v_permlane32_swap_b32 %0, %1" : "+v"(a1), "+v"(b1));
                intx4 w;
                w[0] = (int)a0; w[1] = (int)a1; w[2] = (int)b0; w[3] = (int)b1;
                short8 pa = __builtin_bit_cast(short8, w);
                const int tofs = kt * 32 + kh2 * 16 + hi2 * 8;
                short8 vf0 = *(const short8*)&vrow0[tofs];
                short8 vf1 = *(const short8*)&vrow1[tofs];
                y0 = __builtin_amdgcn_mfma_f32_32x32x16_bf16(pa, vf0, y0, 0, 0, 0);
                y1 = __builtin_amdgcn_mfma_f32_32x32x16_bf16(pa, vf1, y1, 0, 0, 0);
            }
        }

        lsum += __shfl_xor(lsum, 32);
        const float linv = 1.0f / lsum;

        float sc[16];
        #pragma unroll
        for (int r = 0; r < 16; r++)
            sc[r] = __shfl(linv, (r & 3) + 8 * (r >> 2) + 4 * hi2, 64);

        #pragma unroll
        for (int r = 0; r < 16; r++) {
            const int qloc = (r & 3) + 8 * (r >> 2) + 4 * hi2;
            const size_t rowoff = baseY + (size_t)(qb * 32 + qloc) * HD;
            Y[rowoff + qcol]      = f2bf(y0[r] * sc[r]);
            Y[rowoff + 32 + qcol] = f2bf(y1[r] * sc[r]);
        }
    }
}

extern "C" void kernel_launch(void* const* d_in, const int* in_sizes, int n_in,
                              void* d_out, int out_size, void* d_ws, size_t ws_size,
                              hipStream_t stream) {
    const float* x         = (const float*)d_in[0];
    const float* w_kv_down = (const float*)d_in[1];
    const float* w_kv_up   = (const float*)d_in[2];
    const float* w_q       = (const float*)d_in[3];
    const float* w_out     = (const float*)d_in[4];
    float* out = (float*)d_out;

    constexpr int Bb = 64, Tt = 256, Cc = 1024, HD = 1024, R = 128;
    constexpr int M = Bb * Tt;  // 16384

    char* ws = (char*)d_ws;
    auto alloc = [&](size_t bytes) {
        void* p = (void*)ws;
        ws += (bytes + 255) & ~(size_t)255;
        return p;
    };
    u16* xb      = (u16*)alloc((size_t)M * Cc * 2);
    u16* wql_t   = (u16*)alloc((size_t)(HD + R) * Cc * 2);  // rows 0..1023 Wq^T, 1024..1151 Wkvd^T
    u16* wkvu_t  = (u16*)alloc((size_t)2 * HD * R * 2);
    u16* wo_t    = (u16*)alloc((size_t)Cc * HD * 2);
    u16* qh      = (u16*)alloc((size_t)M * HD * 2);      // per-head packed q  [b][h][t][64]
    u16* latentb = (u16*)alloc((size_t)M * R * 2);       // adjacent to qh (MODE 4 epilogue)
    u16* kvb     = (u16*)alloc((size_t)M * 2 * HD * 2);  // kh [b][h][t][64] then vt [b][h][d][t]
    u16* yb      = (u16*)alloc((size_t)M * HD * 2);

    u16* kh  = kvb;
    u16* vtg = kvb + (size_t)M * HD;

    // fused prep: cvt + all weight transposes (one launch)
    prep<<<4480, 256, 0, stream>>>(x, xb, w_q, w_kv_down, w_kv_up, w_out, wql_t, wkvu_t, wo_t);

    // q + latent fused: N=1152 exactly (no padding), grid 128*9 = 1152 (div by 8)
    gemm_bt64<4><<<dim3(128 * 9), 256, 0, stream>>>(xb, wql_t, qh, M, HD + R, Cc, 9);
    // kv = latent @ Wkv_up (M x 2048 x 128) -> K per-head packed + V transposed
    gemm_bt<3><<<dim3(M / 128, 2 * HD / 128), 256, 0, stream>>>(latentb, wkvu_t, kvb, M, 2 * HD, R);
    // attention
    attn_kernel<<<Bb * 16, 256, 0, stream>>>(qh, kh, vtg, yb);
    // out = y @ Wout (M x 1024 x 1024), fp32; grid 128*8 = 1024
    gemm_bt64<0><<<dim3(128 * 8), 256, 0, stream>>>(yb, wo_t, out, M, Cc, HD, 8);
}

// Round 12
// 174.981 us; speedup vs baseline: 1.2860x; 1.1178x over previous
//
#include <hip/hip_runtime.h>
#include <hip/hip_bf16.h>
#include <cstdint>
#include <cstddef>

typedef short short8 __attribute__((ext_vector_type(8)));
typedef float floatx4 __attribute__((ext_vector_type(4)));
typedef float floatx16 __attribute__((ext_vector_type(16)));
typedef unsigned short u16;
typedef unsigned int u32;

__device__ __forceinline__ u16 f2bf(float f) {
    __hip_bfloat16 h = __float2bfloat16(f);
    return __builtin_bit_cast(u16, h);
}

__device__ __forceinline__ void gload_lds16(const void* g, void* l) {
    __builtin_amdgcn_global_load_lds(
        (const __attribute__((address_space(1))) void*)g,
        (__attribute__((address_space(3))) void*)l, 16, 0, 0);
}

// ---------------- fused prep: x f32->bf16 + all weight transposes ----------------
__global__ __launch_bounds__(256) void prep(const float* __restrict__ x, u16* __restrict__ xb,
                                            const float* __restrict__ wq, const float* __restrict__ wkvd,
                                            const float* __restrict__ wkvu, const float* __restrict__ wo,
                                            u16* __restrict__ wql_t, u16* __restrict__ wkvu_t,
                                            u16* __restrict__ wo_t) {
    const int b = blockIdx.x;
    if (b < 2048) {
        const int n4 = 16384 * 1024 / 4;
        for (int i = b * 256 + threadIdx.x; i < n4; i += 2048 * 256) {
            float4 v = ((const float4*)x)[i];
            ushort4 o;
            o.x = f2bf(v.x); o.y = f2bf(v.y); o.z = f2bf(v.z); o.w = f2bf(v.w);
            ((ushort4*)xb)[i] = o;
        }
    } else {
        __shared__ float tile[32][33];
        const float* W; u16* Wt; int K, N, lb;
        if (b < 3072)      { W = wq;   Wt = wql_t;                       K = 1024; N = 1024; lb = b - 2048; }
        else if (b < 3200) { W = wkvd; Wt = wql_t + (size_t)1024 * 1024; K = 1024; N = 128;  lb = b - 3072; }
        else if (b < 3456) { W = wkvu; Wt = wkvu_t;                      K = 128;  N = 2048; lb = b - 3200; }
        else               { W = wo;   Wt = wo_t;                        K = 1024; N = 1024; lb = b - 3456; }
        const int nb = N / 32;
        const int n0 = (lb % nb) * 32, k0 = (lb / nb) * 32;
        const int tx = threadIdx.x & 31, ty = threadIdx.x >> 5;
        #pragma unroll
        for (int i = 0; i < 32; i += 8)
            tile[ty + i][tx] = W[(size_t)(k0 + ty + i) * N + n0 + tx];
        __syncthreads();
        #pragma unroll
        for (int i = 0; i < 32; i += 8)
            Wt[(size_t)(n0 + ty + i) * K + k0 + tx] = f2bf(tile[tx][ty + i]);
    }
}

// ---------------- 128x128 BK=64 bf16 GEMM: C = A[M][K] * Bt[N][K]^T ----------------
// 2-phase m97-class, 256 threads / 4 waves (2x2), wave tile 64x64, single 32KB LDS
// buffer, chunk-XOR involution (0-conflict, measured r6-r11), 4 blocks/CU.
// MODE: 0 = f32 [M][N]; 4 = col<1024 -> per-head packed q [b][h][t][64],
//       col>=1024 -> latent [M][128] appended after q (N=1152).
template <int MODE>
__global__ __launch_bounds__(256, 4) void gemm_bt64(const u16* __restrict__ A, const u16* __restrict__ Bt,
                                                    void* __restrict__ C, int M, int N, int K, int ncols) {
    __shared__ __align__(16) u16 As[128 * 64];
    __shared__ __align__(16) u16 Bs[128 * 64];
    const int tid = threadIdx.x;
    const int lane = tid & 63, wid = tid >> 6;
    const int wr = wid >> 1, wc = wid & 1;
    const int l15 = lane & 15, hi = lane >> 4;

    const int nwg = gridDim.x, q8 = nwg >> 3;
    const int wg = (blockIdx.x & 7) * q8 + (blockIdx.x >> 3);
    const int m0 = (wg / ncols) * 128, n0 = (wg % ncols) * 128;

    const u16* Ab = A + (size_t)m0 * K;
    const u16* Bb = Bt + (size_t)n0 * K;

    u32 soff[4];
    #pragma unroll
    for (int l = 0; l < 4; l++) {
        int p = l * 256 + tid, c = p ^ ((p >> 3) & 7);
        soff[l] = (u32)((c >> 3) * K + (c & 7) * 8);
    }

    int afo[4][2], bfo[4][2];
    #pragma unroll
    for (int i = 0; i < 4; i++) {
        #pragma unroll
        for (int ks = 0; ks < 2; ks++) {
            int ra = wr * 64 + i * 16 + l15;
            afo[i][ks] = ((ra * 8 + ks * 4 + hi) ^ (ra & 7)) * 8;
            int rb = wc * 64 + i * 16 + l15;
            bfo[i][ks] = ((rb * 8 + ks * 4 + hi) ^ (rb & 7)) * 8;
        }
    }

    floatx4 acc[4][4] = {};

    for (int k0 = 0; k0 < K; k0 += 64) {
        #pragma unroll
        for (int l = 0; l < 4; l++)
            gload_lds16(Ab + soff[l] + k0, As + (size_t)(l * 256 + wid * 64) * 8);
        #pragma unroll
        for (int l = 0; l < 4; l++)
            gload_lds16(Bb + soff[l] + k0, Bs + (size_t)(l * 256 + wid * 64) * 8);
        __syncthreads();
        #pragma unroll
        for (int ks = 0; ks < 2; ks++) {
            short8 af[4], bf[4];
            #pragma unroll
            for (int i = 0; i < 4; i++) af[i] = *(const short8*)&As[afo[i][ks]];
            #pragma unroll
            for (int j = 0; j < 4; j++) bf[j] = *(const short8*)&Bs[bfo[j][ks]];
            #pragma unroll
            for (int i = 0; i < 4; i++) {
                #pragma unroll
                for (int j = 0; j < 4; j++)
                    acc[i][j] = __builtin_amdgcn_mfma_f32_16x16x32_bf16(af[i], bf[j], acc[i][j], 0, 0, 0);
            }
        }
        __syncthreads();
    }

    const int cr = hi * 4, cc = l15;
    #pragma unroll
    for (int i = 0; i < 4; i++) {
        #pragma unroll
        for (int j = 0; j < 4; j++) {
            int row = m0 + wr * 64 + i * 16 + cr;
            int col = n0 + wc * 64 + j * 16 + cc;
            #pragma unroll
            for (int r = 0; r < 4; r++) {
                float v = acc[i][j][r];
                int rr = row + r;
                if (MODE == 0) {
                    ((float*)C)[(size_t)rr * N + col] = v;
                } else {  // MODE 4
                    if (col < 1024) {
                        int h = col >> 6, dd = col & 63;
                        ((u16*)C)[(((size_t)(rr >> 8) * 16 + h) * 256 + (rr & 255)) * 64 + dd] = f2bf(v);
                    } else {
                        u16* lat = (u16*)C + (size_t)16384 * 1024;
                        lat[(size_t)rr * 128 + (col - 1024)] = f2bf(v);
                    }
                }
            }
        }
    }
}

// ---------------- fused causal attention: builds K,V from latent in-kernel ----------
// One block per (b,h), 4 waves. Build phase: 32 MFMA tiles (32x32x16, fp32 acc)
// compute K[t][d] = latent·WuK (into swizzled Ks) and Vt[d][t] = WuV·latent^T
// (into padded Vt). latent (4 MB, L3) and Wu (0.5 MB, L2) read straight from
// global. Ks swizzle: chunk c' = c ^ x(t), x(t) = (t&7)^((t>>3)&3) — write and
// read sides both 2-way-max bank pattern (audited). Then the proven 32x32
// attention loop (swapped QK^T, in-register P via permlane32_swap, no max-sub).
__global__ __launch_bounds__(256, 2) void attn_fused(const u16* __restrict__ Qh, const u16* __restrict__ Lat,
                                                     const u16* __restrict__ Wu, u16* __restrict__ Y) {
    constexpr int T = 256, HD = 1024;
    constexpr int VS = 264;
    __shared__ __align__(16) u16 Ks[256 * 64];   // 32 KB, swizzled
    __shared__ __align__(16) u16 Vt[64 * VS];    // 33 KB

    const int tid = threadIdx.x, lane = tid & 63, wid = tid >> 6;
    const int bh = blockIdx.x;
    const int b = bh >> 4, h = bh & 15;
    const size_t base = (size_t)bh * (T * 64);
    const size_t baseY = (size_t)b * T * HD + (size_t)h * 64;

    const int qcol = lane & 31, hi2 = lane >> 5;

    // ---- build K and Vt ----
    {
        const u16* latb = Lat + (size_t)b * 256 * 128;
        const u16* wK = Wu + (size_t)(h * 64) * 128;
        const u16* wV = Wu + (size_t)(1024 + h * 64) * 128;

        #pragma unroll
        for (int i = 0; i < 4; i++) {
            const int tt = wid * 2 + (i >> 1), dt = i & 1;
            const u16* lp = &latb[(size_t)(tt * 32 + qcol) * 128 + hi2 * 8];
            const u16* kp = &wK[(size_t)(dt * 32 + qcol) * 128 + hi2 * 8];
            const u16* vp = &wV[(size_t)(dt * 32 + qcol) * 128 + hi2 * 8];
            floatx16 ck = {0}, cv = {0};
            #pragma unroll
            for (int ks = 0; ks < 8; ks++) {
                short8 lf = *(const short8*)&lp[ks * 16];
                short8 kf = *(const short8*)&kp[ks * 16];
                short8 vf = *(const short8*)&vp[ks * 16];
                ck = __builtin_amdgcn_mfma_f32_32x32x16_bf16(lf, kf, ck, 0, 0, 0);  // C[t][d]
                cv = __builtin_amdgcn_mfma_f32_32x32x16_bf16(vf, lf, cv, 0, 0, 0);  // C[d][t]
            }
            const int dK = dt * 32 + qcol;  // K: lane owns col d
            const int tV = tt * 32 + qcol;  // V: lane owns col t
            #pragma unroll
            for (int r = 0; r < 16; r++) {
                const int rloc = (r & 3) + 8 * (r >> 2) + 4 * hi2;
                const int t = tt * 32 + rloc;
                const int xt = (t & 7) ^ ((t >> 3) & 3);
                Ks[t * 64 + (((dK >> 3) ^ xt) << 3) + (dK & 7)] = f2bf(ck[r]);
                Vt[(dt * 32 + rloc) * VS + tV] = f2bf(cv[r]);
            }
        }
    }
    __syncthreads();

    const float c_exp = 0.125f * 1.44269504088896f;
    const u16* qbase = Qh + base;
    const u16* vrow0 = &Vt[qcol * VS];
    const u16* vrow1 = &Vt[(qcol + 32) * VS];

    #pragma unroll 1
    for (int half = 0; half < 2; half++) {
        const int qb = half ? (7 - wid) : wid;

        short8 qf[4];
        {
            const u16* qp = &qbase[(size_t)(qb * 32 + qcol) * 64 + hi2 * 8];
            #pragma unroll
            for (int i = 0; i < 4; i++) qf[i] = *(const short8*)&qp[i * 16];
        }

        floatx16 y0 = {0}, y1 = {0};
        float lsum = 0.f;

        for (int kt = 0; kt <= qb; kt++) {
            const int tK = kt * 32 + qcol;
            const int xt = (tK & 7) ^ ((tK >> 3) & 3);
            const u16* kp = &Ks[tK * 64];
            floatx16 s = {0};
            #pragma unroll
            for (int i = 0; i < 4; i++) {
                short8 kf = *(const short8*)&kp[((i * 2 + hi2) ^ xt) << 3];
                s = __builtin_amdgcn_mfma_f32_32x32x16_bf16(kf, qf[i], s, 0, 0, 0);
            }

            const bool diag = (kt == qb);
            u32 pk[8];
            #pragma unroll
            for (int r2 = 0; r2 < 8; r2++) {
                const int r0 = 2 * r2;
                const int kr0 = (r0 & 3) + 8 * (r0 >> 2) + 4 * hi2;
                float p0 = exp2f(s[r0] * c_exp);
                float p1 = exp2f(s[r0 + 1] * c_exp);
                if (diag) {
                    if (kr0 > qcol) p0 = 0.f;
                    if (kr0 + 1 > qcol) p1 = 0.f;
                }
                lsum += p0 + p1;
                pk[r2] = (u32)f2bf(p0) | ((u32)f2bf(p1) << 16);
            }

            #pragma unroll
            for (int kh2 = 0; kh2 < 2; kh2++) {
                u32 a0 = pk[kh2 * 4 + 0], a1 = pk[kh2 * 4 + 1];
                u32 b0 = pk[kh2 * 4 + 2], b1 = pk[kh2 * 4 + 3];
                asm volatile("v_permlane32_swap_b32 %0, %1" : "+v"(a0), "+v"(b0));
                asm volatile("v_permlane32_swap_b32 %0, %1" : "+v"(a1), "+v"(b1));
                int4 w;
                w.x = (int)a0; w.y = (int)a1; w.z = (int)b0; w.w = (int)b1;
                short8 pa = __builtin_bit_cast(short8, w);
                const int tofs = kt * 32 + kh2 * 16 + hi2 * 8;
                short8 vf0 = *(const short8*)&vrow0[tofs];
                short8 vf1 = *(const short8*)&vrow1[tofs];
                y0 = __builtin_amdgcn_mfma_f32_32x32x16_bf16(pa, vf0, y0, 0, 0, 0);
                y1 = __builtin_amdgcn_mfma_f32_32x32x16_bf16(pa, vf1, y1, 0, 0, 0);
            }
        }

        lsum += __shfl_xor(lsum, 32);
        const float linv = 1.0f / lsum;

        float sc[16];
        #pragma unroll
        for (int r = 0; r < 16; r++)
            sc[r] = __shfl(linv, (r & 3) + 8 * (r >> 2) + 4 * hi2, 64);

        #pragma unroll
        for (int r = 0; r < 16; r++) {
            const int qloc = (r & 3) + 8 * (r >> 2) + 4 * hi2;
            const size_t rowoff = baseY + (size_t)(qb * 32 + qloc) * HD;
            Y[rowoff + qcol]      = f2bf(y0[r] * sc[r]);
            Y[rowoff + 32 + qcol] = f2bf(y1[r] * sc[r]);
        }
    }
}

extern "C" void kernel_launch(void* const* d_in, const int* in_sizes, int n_in,
                              void* d_out, int out_size, void* d_ws, size_t ws_size,
                              hipStream_t stream) {
    const float* x         = (const float*)d_in[0];
    const float* w_kv_down = (const float*)d_in[1];
    const float* w_kv_up   = (const float*)d_in[2];
    const float* w_q       = (const float*)d_in[3];
    const float* w_out     = (const float*)d_in[4];
    float* out = (float*)d_out;

    constexpr int Bb = 64, Tt = 256, Cc = 1024, HD = 1024, R = 128;
    constexpr int M = Bb * Tt;  // 16384

    char* ws = (char*)d_ws;
    auto alloc = [&](size_t bytes) {
        void* p = (void*)ws;
        ws += (bytes + 255) & ~(size_t)255;
        return p;
    };
    u16* xb      = (u16*)alloc((size_t)M * Cc * 2);
    u16* wql_t   = (u16*)alloc((size_t)(HD + R) * Cc * 2);  // rows 0..1023 Wq^T, 1024..1151 Wkvd^T
    u16* wkvu_t  = (u16*)alloc((size_t)2 * HD * R * 2);
    u16* wo_t    = (u16*)alloc((size_t)Cc * HD * 2);
    u16* qh      = (u16*)alloc((size_t)M * HD * 2);      // per-head packed q  [b][h][t][64]
    u16* latentb = (u16*)alloc((size_t)M * R * 2);       // adjacent to qh (MODE 4 epilogue)
    u16* yb      = (u16*)alloc((size_t)M * HD * 2);

    // fused prep: cvt + all weight transposes (one launch)
    prep<<<4480, 256, 0, stream>>>(x, xb, w_q, w_kv_down, w_kv_up, w_out, wql_t, wkvu_t, wo_t);

    // q + latent fused: N=1152 exactly, grid 128*9 = 1152 (div by 8)
    gemm_bt64<4><<<dim3(128 * 9), 256, 0, stream>>>(xb, wql_t, qh, M, HD + R, Cc, 9);
    // fused attention (builds K,V from latent in-kernel; kv GEMM eliminated)
    attn_fused<<<Bb * 16, 256, 0, stream>>>(qh, latentb, wkvu_t, yb);
    // out = y @ Wout (M x 1024 x 1024), fp32; grid 128*8 = 1024
    gemm_bt64<0><<<dim3(128 * 8), 256, 0, stream>>>(yb, wo_t, out, M, Cc, HD, 8);
}

// Round 13
// 152.243 us; speedup vs baseline: 1.4780x; 1.1494x over previous
//
#include <hip/hip_runtime.h>
#include <hip/hip_bf16.h>
#include <cstdint>
#include <cstddef>

typedef short short8 __attribute__((ext_vector_type(8)));
typedef float floatx4 __attribute__((ext_vector_type(4)));
typedef float floatx16 __attribute__((ext_vector_type(16)));
typedef unsigned short u16;
typedef unsigned int u32;

__device__ __forceinline__ u16 f2bf(float f) {
    __hip_bfloat16 h = __float2bfloat16(f);
    return __builtin_bit_cast(u16, h);
}

__device__ __forceinline__ void gload_lds16(const void* g, void* l) {
    __builtin_amdgcn_global_load_lds(
        (const __attribute__((address_space(1))) void*)g,
        (__attribute__((address_space(3))) void*)l, 16, 0, 0);
}

// ---------------- fused prep: x f32->bf16 + all weight transposes ----------------
__global__ __launch_bounds__(256) void prep(const float* __restrict__ x, u16* __restrict__ xb,
                                            const float* __restrict__ wq, const float* __restrict__ wkvd,
                                            const float* __restrict__ wkvu, const float* __restrict__ wo,
                                            u16* __restrict__ wql_t, u16* __restrict__ wkvu_t,
                                            u16* __restrict__ wo_t) {
    const int b = blockIdx.x;
    if (b < 2048) {
        const int n4 = 16384 * 1024 / 4;
        for (int i = b * 256 + threadIdx.x; i < n4; i += 2048 * 256) {
            float4 v = ((const float4*)x)[i];
            ushort4 o;
            o.x = f2bf(v.x); o.y = f2bf(v.y); o.z = f2bf(v.z); o.w = f2bf(v.w);
            ((ushort4*)xb)[i] = o;
        }
    } else {
        __shared__ float tile[32][33];
        const float* W; u16* Wt; int K, N, lb;
        if (b < 3072)      { W = wq;   Wt = wql_t;                       K = 1024; N = 1024; lb = b - 2048; }
        else if (b < 3200) { W = wkvd; Wt = wql_t + (size_t)1024 * 1024; K = 1024; N = 128;  lb = b - 3072; }
        else if (b < 3456) { W = wkvu; Wt = wkvu_t;                      K = 128;  N = 2048; lb = b - 3200; }
        else               { W = wo;   Wt = wo_t;                        K = 1024; N = 1024; lb = b - 3456; }
        const int nb = N / 32;
        const int n0 = (lb % nb) * 32, k0 = (lb / nb) * 32;
        const int tx = threadIdx.x & 31, ty = threadIdx.x >> 5;
        #pragma unroll
        for (int i = 0; i < 32; i += 8)
            tile[ty + i][tx] = W[(size_t)(k0 + ty + i) * N + n0 + tx];
        __syncthreads();
        #pragma unroll
        for (int i = 0; i < 32; i += 8)
            Wt[(size_t)(n0 + ty + i) * K + k0 + tx] = f2bf(tile[tx][ty + i]);
    }
}

// ---------------- 128x128 BK=64 bf16 GEMM: C = A[M][K] * Bt[N][K]^T ----------------
// 2-phase m97-class, 256 threads / 4 waves (2x2), wave tile 64x64, single 32KB LDS
// buffer, chunk-XOR involution (0-conflict, measured r6-r12), 4 blocks/CU.
template <int MODE>
__global__ __launch_bounds__(256, 4) void gemm_bt64(const u16* __restrict__ A, const u16* __restrict__ Bt,
                                                    void* __restrict__ C, int M, int N, int K, int ncols) {
    __shared__ __align__(16) u16 As[128 * 64];
    __shared__ __align__(16) u16 Bs[128 * 64];
    const int tid = threadIdx.x;
    const int lane = tid & 63, wid = tid >> 6;
    const int wr = wid >> 1, wc = wid & 1;
    const int l15 = lane & 15, hi = lane >> 4;

    const int nwg = gridDim.x, q8 = nwg >> 3;
    const int wg = (blockIdx.x & 7) * q8 + (blockIdx.x >> 3);
    const int m0 = (wg / ncols) * 128, n0 = (wg % ncols) * 128;

    const u16* Ab = A + (size_t)m0 * K;
    const u16* Bb = Bt + (size_t)n0 * K;

    u32 soff[4];
    #pragma unroll
    for (int l = 0; l < 4; l++) {
        int p = l * 256 + tid, c = p ^ ((p >> 3) & 7);
        soff[l] = (u32)((c >> 3) * K + (c & 7) * 8);
    }

    int afo[4][2], bfo[4][2];
    #pragma unroll
    for (int i = 0; i < 4; i++) {
        #pragma unroll
        for (int ks = 0; ks < 2; ks++) {
            int ra = wr * 64 + i * 16 + l15;
            afo[i][ks] = ((ra * 8 + ks * 4 + hi) ^ (ra & 7)) * 8;
            int rb = wc * 64 + i * 16 + l15;
            bfo[i][ks] = ((rb * 8 + ks * 4 + hi) ^ (rb & 7)) * 8;
        }
    }

    floatx4 acc[4][4] = {};

    for (int k0 = 0; k0 < K; k0 += 64) {
        #pragma unroll
        for (int l = 0; l < 4; l++)
            gload_lds16(Ab + soff[l] + k0, As + (size_t)(l * 256 + wid * 64) * 8);
        #pragma unroll
        for (int l = 0; l < 4; l++)
            gload_lds16(Bb + soff[l] + k0, Bs + (size_t)(l * 256 + wid * 64) * 8);
        __syncthreads();
        #pragma unroll
        for (int ks = 0; ks < 2; ks++) {
            short8 af[4], bf[4];
            #pragma unroll
            for (int i = 0; i < 4; i++) af[i] = *(const short8*)&As[afo[i][ks]];
            #pragma unroll
            for (int j = 0; j < 4; j++) bf[j] = *(const short8*)&Bs[bfo[j][ks]];
            #pragma unroll
            for (int i = 0; i < 4; i++) {
                #pragma unroll
                for (int j = 0; j < 4; j++)
                    acc[i][j] = __builtin_amdgcn_mfma_f32_16x16x32_bf16(af[i], bf[j], acc[i][j], 0, 0, 0);
            }
        }
        __syncthreads();
    }

    const int cr = hi * 4, cc = l15;
    #pragma unroll
    for (int i = 0; i < 4; i++) {
        #pragma unroll
        for (int j = 0; j < 4; j++) {
            int row = m0 + wr * 64 + i * 16 + cr;
            int col = n0 + wc * 64 + j * 16 + cc;
            #pragma unroll
            for (int r = 0; r < 4; r++) {
                float v = acc[i][j][r];
                int rr = row + r;
                if (MODE == 0) {
                    ((float*)C)[(size_t)rr * N + col] = v;
                } else {  // MODE 4
                    if (col < 1024) {
                        int h = col >> 6, dd = col & 63;
                        ((u16*)C)[(((size_t)(rr >> 8) * 16 + h) * 256 + (rr & 255)) * 64 + dd] = f2bf(v);
                    } else {
                        u16* lat = (u16*)C + (size_t)16384 * 1024;
                        lat[(size_t)rr * 128 + (col - 1024)] = f2bf(v);
                    }
                }
            }
        }
    }
}

// ---------------- fused causal attention: builds K,V from latent in-kernel ----------
// One block per (b,h), 4 waves. Build v2: latent[256][128] is STAGED into the
// Ks∪Vt union space (64KB fits the 66.5KB union) via 16 coalesced global_load_lds
// per thread with within-row chunk-XOR (p = c ^ ((c>>4)&15), conflict-free b128
// reads). K/V tiles are computed into registers (ck/cv, 128 VGPR, static index),
// then after a barrier (all lat reads retired) written over the union as swizzled
// Ks + padded Vt — identical write/read layout to r12 (verified). Weight frags
// loaded once per (dt,ks), reused by both t-tiles (32 global loads vs r12's 64;
// lat's 32 scattered 32-line loads removed entirely).
__global__ __launch_bounds__(256, 2) void attn_fused(const u16* __restrict__ Qh, const u16* __restrict__ Lat,
                                                     const u16* __restrict__ Wu, u16* __restrict__ Y) {
    constexpr int T = 256, HD = 1024;
    constexpr int VS = 264;
    __shared__ __align__(16) u16 lds[33280];     // union: lat[32768] / Ks[16384]+Vt[16896]
    u16* Ks = lds;
    u16* Vt = lds + 16384;

    const int tid = threadIdx.x, lane = tid & 63, wid = tid >> 6;
    const int bh = blockIdx.x;
    const int b = bh >> 4, h = bh & 15;
    const size_t base = (size_t)bh * (T * 64);
    const size_t baseY = (size_t)b * T * HD + (size_t)h * 64;

    const int qcol = lane & 31, hi2 = lane >> 5;

    // ---- stage latent (coalesced, chunk-XOR involution within each 16-chunk row) ----
    {
        const u16* latb = Lat + (size_t)b * 256 * 128;
        #pragma unroll
        for (int l = 0; l < 16; l++) {
            int p = l * 256 + tid;
            int c = p ^ ((p >> 4) & 15);
            gload_lds16(latb + (size_t)c * 8, lds + (size_t)(l * 256 + wid * 64) * 8);
        }
    }
    __syncthreads();

    // ---- build K,V tiles in registers from LDS latent + global weights ----
    floatx16 ck[4] = {}, cv[4] = {};   // i = it*2 + dt; tt = wid*2+it
    {
        const u16* wK = Wu + (size_t)(h * 64) * 128;
        const u16* wV = Wu + (size_t)(1024 + h * 64) * 128;
        #pragma unroll
        for (int ks = 0; ks < 8; ks++) {
            short8 kf[2], vf[2];
            #pragma unroll
            for (int dt = 0; dt < 2; dt++) {
                kf[dt] = *(const short8*)&wK[(size_t)(dt * 32 + qcol) * 128 + hi2 * 8 + ks * 16];
                vf[dt] = *(const short8*)&wV[(size_t)(dt * 32 + qcol) * 128 + hi2 * 8 + ks * 16];
            }
            #pragma unroll
            for (int it = 0; it < 2; it++) {
                const int row = (wid * 2 + it) * 32 + qcol;
                const int c = row * 16 + hi2 + 2 * ks;
                short8 lf = *(const short8*)&lds[(size_t)(c ^ (row & 15)) * 8];
                #pragma unroll
                for (int dt = 0; dt < 2; dt++) {
                    ck[it * 2 + dt] = __builtin_amdgcn_mfma_f32_32x32x16_bf16(lf, kf[dt], ck[it * 2 + dt], 0, 0, 0);  // C[t][d]
                    cv[it * 2 + dt] = __builtin_amdgcn_mfma_f32_32x32x16_bf16(vf[dt], lf, cv[it * 2 + dt], 0, 0, 0);  // C[d][t]
                }
            }
        }
    }
    __syncthreads();   // all latent reads retired -> safe to overwrite union

    // ---- write Ks (swizzled) and Vt (padded) — layout identical to r12 ----
    #pragma unroll
    for (int i = 0; i < 4; i++) {
        const int tt = wid * 2 + (i >> 1), dt = i & 1;
        const int dK = dt * 32 + qcol;
        const int tV = tt * 32 + qcol;
        #pragma unroll
        for (int r = 0; r < 16; r++) {
            const int rloc = (r & 3) + 8 * (r >> 2) + 4 * hi2;
            const int t = tt * 32 + rloc;
            const int xt = (t & 7) ^ ((t >> 3) & 3);
            Ks[t * 64 + (((dK >> 3) ^ xt) << 3) + (dK & 7)] = f2bf(ck[i][r]);
            Vt[(dt * 32 + rloc) * VS + tV] = f2bf(cv[i][r]);
        }
    }
    __syncthreads();

    const float c_exp = 0.125f * 1.44269504088896f;
    const u16* qbase = Qh + base;
    const u16* vrow0 = &Vt[qcol * VS];
    const u16* vrow1 = &Vt[(qcol + 32) * VS];

    #pragma unroll 1
    for (int half = 0; half < 2; half++) {
        const int qb = half ? (7 - wid) : wid;

        short8 qf[4];
        {
            const u16* qp = &qbase[(size_t)(qb * 32 + qcol) * 64 + hi2 * 8];
            #pragma unroll
            for (int i = 0; i < 4; i++) qf[i] = *(const short8*)&qp[i * 16];
        }

        floatx16 y0 = {0}, y1 = {0};
        float lsum = 0.f;

        for (int kt = 0; kt <= qb; kt++) {
            const int tK = kt * 32 + qcol;
            const int xt = (tK & 7) ^ ((tK >> 3) & 3);
            const u16* kp = &Ks[tK * 64];
            floatx16 s = {0};
            #pragma unroll
            for (int i = 0; i < 4; i++) {
                short8 kf = *(const short8*)&kp[((i * 2 + hi2) ^ xt) << 3];
                s = __builtin_amdgcn_mfma_f32_32x32x16_bf16(kf, qf[i], s, 0, 0, 0);
            }

            const bool diag = (kt == qb);
            u32 pk[8];
            #pragma unroll
            for (int r2 = 0; r2 < 8; r2++) {
                const int r0 = 2 * r2;
                const int kr0 = (r0 & 3) + 8 * (r0 >> 2) + 4 * hi2;
                float p0 = exp2f(s[r0] * c_exp);
                float p1 = exp2f(s[r0 + 1] * c_exp);
                if (diag) {
                    if (kr0 > qcol) p0 = 0.f;
                    if (kr0 + 1 > qcol) p1 = 0.f;
                }
                lsum += p0 + p1;
                pk[r2] = (u32)f2bf(p0) | ((u32)f2bf(p1) << 16);
            }

            #pragma unroll
            for (int kh2 = 0; kh2 < 2; kh2++) {
                u32 a0 = pk[kh2 * 4 + 0], a1 = pk[kh2 * 4 + 1];
                u32 b0 = pk[kh2 * 4 + 2], b1 = pk[kh2 * 4 + 3];
                asm volatile("v_permlane32_swap_b32 %0, %1" : "+v"(a0), "+v"(b0));
                asm volatile("v_permlane32_swap_b32 %0, %1" : "+v"(a1), "+v"(b1));
                int4 w;
                w.x = (int)a0; w.y = (int)a1; w.z = (int)b0; w.w = (int)b1;
                short8 pa = __builtin_bit_cast(short8, w);
                const int tofs = kt * 32 + kh2 * 16 + hi2 * 8;
                short8 vf0 = *(const short8*)&vrow0[tofs];
                short8 vf1 = *(const short8*)&vrow1[tofs];
                y0 = __builtin_amdgcn_mfma_f32_32x32x16_bf16(pa, vf0, y0, 0, 0, 0);
                y1 = __builtin_amdgcn_mfma_f32_32x32x16_bf16(pa, vf1, y1, 0, 0, 0);
            }
        }

        lsum += __shfl_xor(lsum, 32);
        const float linv = 1.0f / lsum;

        float sc[16];
        #pragma unroll
        for (int r = 0; r < 16; r++)
            sc[r] = __shfl(linv, (r & 3) + 8 * (r >> 2) + 4 * hi2, 64);

        #pragma unroll
        for (int r = 0; r < 16; r++) {
            const int qloc = (r & 3) + 8 * (r >> 2) + 4 * hi2;
            const size_t rowoff = baseY + (size_t)(qb * 32 + qloc) * HD;
            Y[rowoff + qcol]      = f2bf(y0[r] * sc[r]);
            Y[rowoff + 32 + qcol] = f2bf(y1[r] * sc[r]);
        }
    }
}

extern "C" void kernel_launch(void* const* d_in, const int* in_sizes, int n_in,
                              void* d_out, int out_size, void* d_ws, size_t ws_size,
                              hipStream_t stream) {
    const float* x         = (const float*)d_in[0];
    const float* w_kv_down = (const float*)d_in[1];
    const float* w_kv_up   = (const float*)d_in[2];
    const float* w_q       = (const float*)d_in[3];
    const float* w_out     = (const float*)d_in[4];
    float* out = (float*)d_out;

    constexpr int Bb = 64, Tt = 256, Cc = 1024, HD = 1024, R = 128;
    constexpr int M = Bb * Tt;  // 16384

    char* ws = (char*)d_ws;
    auto alloc = [&](size_t bytes) {
        void* p = (void*)ws;
        ws += (bytes + 255) & ~(size_t)255;
        return p;
    };
    u16* xb      = (u16*)alloc((size_t)M * Cc * 2);
    u16* wql_t   = (u16*)alloc((size_t)(HD + R) * Cc * 2);  // rows 0..1023 Wq^T, 1024..1151 Wkvd^T
    u16* wkvu_t  = (u16*)alloc((size_t)2 * HD * R * 2);
    u16* wo_t    = (u16*)alloc((size_t)Cc * HD * 2);
    u16* qh      = (u16*)alloc((size_t)M * HD * 2);      // per-head packed q  [b][h][t][64]
    u16* latentb = (u16*)alloc((size_t)M * R * 2);       // adjacent to qh (MODE 4 epilogue)
    u16* yb      = (u16*)alloc((size_t)M * HD * 2);

    // fused prep: cvt + all weight transposes (one launch)
    prep<<<4480, 256, 0, stream>>>(x, xb, w_q, w_kv_down, w_kv_up, w_out, wql_t, wkvu_t, wo_t);

    // q + latent fused: N=1152 exactly, grid 128*9 = 1152 (div by 8)
    gemm_bt64<4><<<dim3(128 * 9), 256, 0, stream>>>(xb, wql_t, qh, M, HD + R, Cc, 9);
    // fused attention (builds K,V from latent in-kernel)
    attn_fused<<<Bb * 16, 256, 0, stream>>>(qh, latentb, wkvu_t, yb);
    // out = y @ Wout (M x 1024 x 1024), fp32; grid 128*8 = 1024
    gemm_bt64<0><<<dim3(128 * 8), 256, 0, stream>>>(yb, wo_t, out, M, Cc, HD, 8);
}